// Round 1
// baseline (662.822 us; speedup 1.0000x reference)
//
#include <hip/hip_runtime.h>
#include <hip/hip_bf16.h>
#include <math.h>

// GCN 2-layer: x[N,128] @ W1 -> agg -> relu -> @ W2 -> agg -> log_softmax
// N=100000, E=1600000, F=128, H=64, C=40

#define NFEAT 128
#define HID 64
#define NCLS 40

// ---------------- setup kernels ----------------

__global__ __launch_bounds__(256) void k_init(float* deg, int* cnt, int* fill, int n) {
    int i = blockIdx.x * 256 + threadIdx.x;
    if (i < n) { deg[i] = 1.0f; cnt[i] = 0; fill[i] = 0; }
}

__global__ __launch_bounds__(256) void k_deg_cnt(const int* __restrict__ dst,
                                                 const float* __restrict__ w,
                                                 float* deg, int* cnt, int e) {
    for (int i = blockIdx.x * 256 + threadIdx.x; i < e; i += gridDim.x * 256) {
        int d = dst[i];
        atomicAdd(&deg[d], w[i]);
        atomicAdd(&cnt[d], 1);
    }
}

__global__ __launch_bounds__(256) void k_dinv(float* deg, int n) {
    int i = blockIdx.x * 256 + threadIdx.x;
    if (i < n) { float d = deg[i]; deg[i] = d > 0.f ? rsqrtf(d) : 0.f; }
}

// exclusive prefix scan of cnt[N] -> rowptr[N+1], 3 kernels, 1024 elems/block
__global__ __launch_bounds__(256) void k_scan_partial(const int* __restrict__ cnt, int* bsum, int n) {
    __shared__ int s[256];
    int t = threadIdx.x;
    int base = blockIdx.x * 1024;
    int sum = 0;
#pragma unroll
    for (int j = 0; j < 4; j++) { int idx = base + t * 4 + j; sum += (idx < n) ? cnt[idx] : 0; }
    s[t] = sum; __syncthreads();
    for (int off = 128; off > 0; off >>= 1) { if (t < off) s[t] += s[t + off]; __syncthreads(); }
    if (t == 0) bsum[blockIdx.x] = s[0];
}

__global__ void k_scan_blk(const int* __restrict__ bsum, int* boff, int* rowptr, int nblk, int n) {
    if (threadIdx.x == 0 && blockIdx.x == 0) {
        int run = 0;
        for (int b = 0; b < nblk; b++) { boff[b] = run; run += bsum[b]; }
        rowptr[n] = run;
    }
}

__global__ __launch_bounds__(256) void k_scan_final(const int* __restrict__ cnt,
                                                    const int* __restrict__ boff,
                                                    int* rowptr, int n) {
    __shared__ int s[256];
    int t = threadIdx.x;
    int base = blockIdx.x * 1024;
    int v[4]; int sum = 0;
#pragma unroll
    for (int j = 0; j < 4; j++) { int idx = base + t * 4 + j; v[j] = (idx < n) ? cnt[idx] : 0; sum += v[j]; }
    s[t] = sum; __syncthreads();
    for (int off = 1; off < 256; off <<= 1) {
        int x = (t >= off) ? s[t - off] : 0;
        __syncthreads();
        s[t] += x;
        __syncthreads();
    }
    int excl = (t > 0 ? s[t - 1] : 0) + boff[blockIdx.x];
#pragma unroll
    for (int j = 0; j < 4; j++) { int idx = base + t * 4 + j; if (idx < n) rowptr[idx] = excl; excl += v[j]; }
}

__global__ __launch_bounds__(256) void k_scatter(const int* __restrict__ src,
                                                 const int* __restrict__ dst,
                                                 const float* __restrict__ w,
                                                 const float* __restrict__ dinv,
                                                 const int* __restrict__ rowptr,
                                                 int* fill, int* col, float* val, int e) {
    for (int i = blockIdx.x * 256 + threadIdx.x; i < e; i += gridDim.x * 256) {
        int s = src[i], d = dst[i];
        int pos = rowptr[d] + atomicAdd(&fill[d], 1);
        col[pos] = s;
        val[pos] = dinv[s] * w[i] * dinv[d];
    }
}

// ---------------- GEMMs (wave per row, weights in registers) ----------------

__global__ __launch_bounds__(256) void k_gemm1(const float* __restrict__ x,
                                               const float* __restrict__ W1,
                                               float* __restrict__ h1, int n) {
    int lane = threadIdx.x & 63;
    int wid = threadIdx.x >> 6;
    float w[NFEAT];
#pragma unroll
    for (int k = 0; k < NFEAT; k++) w[k] = W1[k * HID + lane];
    int wave = blockIdx.x * 4 + wid;
    int nwaves = gridDim.x * 4;
    for (int row = wave; row < n; row += nwaves) {
        int r = __builtin_amdgcn_readfirstlane(row);
        const float4* xp = reinterpret_cast<const float4*>(x + (size_t)r * NFEAT);
        float acc = 0.f;
#pragma unroll
        for (int k0 = 0; k0 < NFEAT / 4; k0++) {
            float4 xv = xp[k0];
            acc = fmaf(xv.x, w[4 * k0 + 0], acc);
            acc = fmaf(xv.y, w[4 * k0 + 1], acc);
            acc = fmaf(xv.z, w[4 * k0 + 2], acc);
            acc = fmaf(xv.w, w[4 * k0 + 3], acc);
        }
        h1[(size_t)r * HID + lane] = acc;
    }
}

__global__ __launch_bounds__(256) void k_gemm2(const float* __restrict__ y,
                                               const float* __restrict__ W2,
                                               float* __restrict__ h2, int n) {
    int lane = threadIdx.x & 63;
    int wid = threadIdx.x >> 6;
    int c = lane < NCLS ? lane : 0;
    float w[HID];
#pragma unroll
    for (int k = 0; k < HID; k++) w[k] = W2[k * NCLS + c];
    int wave = blockIdx.x * 4 + wid;
    int nwaves = gridDim.x * 4;
    for (int row = wave; row < n; row += nwaves) {
        int r = __builtin_amdgcn_readfirstlane(row);
        const float4* yp = reinterpret_cast<const float4*>(y + (size_t)r * HID);
        float acc = 0.f;
#pragma unroll
        for (int k0 = 0; k0 < HID / 4; k0++) {
            float4 yv = yp[k0];
            acc = fmaf(yv.x, w[4 * k0 + 0], acc);
            acc = fmaf(yv.y, w[4 * k0 + 1], acc);
            acc = fmaf(yv.z, w[4 * k0 + 2], acc);
            acc = fmaf(yv.w, w[4 * k0 + 3], acc);
        }
        if (lane < NCLS) h2[(size_t)r * NCLS + lane] = acc;
    }
}

// ---------------- aggregations (wave per node, lane = feature) ----------------

__global__ __launch_bounds__(256) void k_agg1(const float* __restrict__ h1,
                                              const int* __restrict__ rowptr,
                                              const int* __restrict__ col,
                                              const float* __restrict__ val,
                                              const float* __restrict__ dinv,
                                              const float* __restrict__ b1,
                                              float* __restrict__ y, int n) {
    int lane = threadIdx.x & 63;
    int wid = threadIdx.x >> 6;
    for (int node = blockIdx.x * 4 + wid; node < n; node += gridDim.x * 4) {
        int i = __builtin_amdgcn_readfirstlane(node);
        float di = dinv[i];
        float acc = di * di * h1[(size_t)i * HID + lane];
        int s = rowptr[i], e = rowptr[i + 1];
        for (int p = s; p < e; p++) {
            int c = col[p];
            float v = val[p];
            acc = fmaf(v, h1[(size_t)c * HID + lane], acc);
        }
        acc += b1[lane];
        y[(size_t)i * HID + lane] = fmaxf(acc, 0.f);
    }
}

__global__ __launch_bounds__(256) void k_agg2(const float* __restrict__ h2,
                                              const int* __restrict__ rowptr,
                                              const int* __restrict__ col,
                                              const float* __restrict__ val,
                                              const float* __restrict__ dinv,
                                              const float* __restrict__ b2,
                                              float* __restrict__ out, int n) {
    int lane = threadIdx.x & 63;
    int wid = threadIdx.x >> 6;
    for (int node = blockIdx.x * 4 + wid; node < n; node += gridDim.x * 4) {
        int i = __builtin_amdgcn_readfirstlane(node);
        float di = dinv[i];
        int c = lane < NCLS ? lane : 0;
        float acc = di * di * h2[(size_t)i * NCLS + c];
        int s = rowptr[i], e = rowptr[i + 1];
        for (int p = s; p < e; p++) {
            int cc = col[p];
            float v = val[p];
            acc = fmaf(v, h2[(size_t)cc * NCLS + c], acc);
        }
        acc += b2[c];
        float z = lane < NCLS ? acc : -INFINITY;
        float m = z;
#pragma unroll
        for (int off = 32; off > 0; off >>= 1) m = fmaxf(m, __shfl_xor(m, off));
        float ex = lane < NCLS ? expf(z - m) : 0.f;
        float ssum = ex;
#pragma unroll
        for (int off = 32; off > 0; off >>= 1) ssum += __shfl_xor(ssum, off);
        if (lane < NCLS) out[(size_t)i * NCLS + lane] = z - m - logf(ssum);
    }
}

// ---------------- launch ----------------

extern "C" void kernel_launch(void* const* d_in, const int* in_sizes, int n_in,
                              void* d_out, int out_size, void* d_ws, size_t ws_size,
                              hipStream_t stream) {
    const float* x = (const float*)d_in[0];
    const int* edge_index = (const int*)d_in[1];
    const float* ew = (const float*)d_in[2];
    const float* W1 = (const float*)d_in[3];
    const float* b1 = (const float*)d_in[4];
    const float* W2 = (const float*)d_in[5];
    const float* b2 = (const float*)d_in[6];
    float* out = (float*)d_out;

    const int N = in_sizes[0] / NFEAT;      // 100000
    const int E = in_sizes[2];              // 1600000
    const int* src = edge_index;
    const int* dst = edge_index + E;

    char* ws = (char*)d_ws;
    float* deg    = (float*)(ws + 0);                 // N floats (becomes dinv)
    int*   cnt    = (int*)(ws + (1u << 20));          // N ints
    int*   rowptr = (int*)(ws + (2u << 20));          // N+1 ints
    int*   fill   = (int*)(ws + (3u << 20));          // N ints
    int*   bsum   = (int*)(ws + (4u << 20));          // scan partials
    int*   boff   = (int*)(ws + (4u << 20) + 16384);
    int*   col    = (int*)(ws + (8u << 20));          // E ints
    float* val    = (float*)(ws + (16u << 20));       // E floats
    float* h1     = (float*)(ws + (24u << 20));       // N*64 floats
    float* y      = (float*)(ws + (52u << 20));       // N*64 floats
    float* h2     = h1;                               // N*40 floats (h1 dead after agg1)

    const int nblkN = (N + 255) / 256;
    const int nblkScan = (N + 1023) / 1024;

    k_init<<<nblkN, 256, 0, stream>>>(deg, cnt, fill, N);
    k_deg_cnt<<<2048, 256, 0, stream>>>(dst, ew, deg, cnt, E);
    k_dinv<<<nblkN, 256, 0, stream>>>(deg, N);
    k_scan_partial<<<nblkScan, 256, 0, stream>>>(cnt, bsum, N);
    k_scan_blk<<<1, 64, 0, stream>>>(bsum, boff, rowptr, nblkScan, N);
    k_scan_final<<<nblkScan, 256, 0, stream>>>(cnt, boff, rowptr, N);
    k_scatter<<<2048, 256, 0, stream>>>(src, dst, ew, deg, rowptr, fill, col, val, E);
    k_gemm1<<<4096, 256, 0, stream>>>(x, W1, h1, N);
    k_agg1<<<(N + 3) / 4, 256, 0, stream>>>(h1, rowptr, col, val, deg, b1, y, N);
    k_gemm2<<<4096, 256, 0, stream>>>(y, W2, h2, N);
    k_agg2<<<(N + 3) / 4, 256, 0, stream>>>(h2, rowptr, col, val, deg, b2, out, N);
}

// Round 2
// 448.891 us; speedup vs baseline: 1.4766x; 1.4766x over previous
//
#include <hip/hip_runtime.h>
#include <hip/hip_bf16.h>
#include <math.h>

// GCN 2-layer: x[N,128] @ W1 -> agg -> relu -> @ W2 -> agg -> log_softmax
// N=100000, E=1600000, F=128, H=64, C=40

#define NFEAT 128
#define HID 64
#define NCLS 40

// deg+cnt packed in u64: high 32 = sum(w)*2^24 fixed point, low 32 = count.
// Self-loop weight 1.0 -> init = 2^24 << 32 = 1<<56.

__global__ __launch_bounds__(256) void k_init(unsigned long long* packed, int n) {
    int i = blockIdx.x * 256 + threadIdx.x;
    if (i < n) packed[i] = 1ull << 56;
}

__global__ __launch_bounds__(256) void k_deg_cnt(const int* __restrict__ dst,
                                                 const float* __restrict__ w,
                                                 unsigned long long* packed,
                                                 unsigned* __restrict__ eord, int e) {
    for (int i = blockIdx.x * 256 + threadIdx.x; i < e; i += gridDim.x * 256) {
        int d = dst[i];
        unsigned wq = (unsigned)(w[i] * 16777216.0f);
        unsigned long long inc = ((unsigned long long)wq << 32) | 1ull;
        unsigned long long old = atomicAdd(&packed[d], inc);
        eord[i] = (unsigned)(old & 0xffffffffull);   // slot within dst's row
    }
}

__global__ __launch_bounds__(256) void k_dinv(const unsigned long long* __restrict__ packed,
                                              float* dinv, int* cnt, int n) {
    int i = blockIdx.x * 256 + threadIdx.x;
    if (i < n) {
        unsigned long long p = packed[i];
        cnt[i] = (int)(p & 0xffffffffull);
        float deg = (float)(unsigned)(p >> 32) * (1.0f / 16777216.0f);
        dinv[i] = deg > 0.f ? rsqrtf(deg) : 0.f;
    }
}

// exclusive prefix scan of cnt[N] -> rowptr[N+1], 3 kernels, 1024 elems/block
__global__ __launch_bounds__(256) void k_scan_partial(const int* __restrict__ cnt, int* bsum, int n) {
    __shared__ int s[256];
    int t = threadIdx.x;
    int base = blockIdx.x * 1024;
    int sum = 0;
#pragma unroll
    for (int j = 0; j < 4; j++) { int idx = base + t * 4 + j; sum += (idx < n) ? cnt[idx] : 0; }
    s[t] = sum; __syncthreads();
    for (int off = 128; off > 0; off >>= 1) { if (t < off) s[t] += s[t + off]; __syncthreads(); }
    if (t == 0) bsum[blockIdx.x] = s[0];
}

__global__ void k_scan_blk(const int* __restrict__ bsum, int* boff, int* rowptr, int nblk, int n) {
    if (threadIdx.x == 0 && blockIdx.x == 0) {
        int run = 0;
        for (int b = 0; b < nblk; b++) { boff[b] = run; run += bsum[b]; }
        rowptr[n] = run;
    }
}

__global__ __launch_bounds__(256) void k_scan_final(const int* __restrict__ cnt,
                                                    const int* __restrict__ boff,
                                                    int* rowptr, int n) {
    __shared__ int s[256];
    int t = threadIdx.x;
    int base = blockIdx.x * 1024;
    int v[4]; int sum = 0;
#pragma unroll
    for (int j = 0; j < 4; j++) { int idx = base + t * 4 + j; v[j] = (idx < n) ? cnt[idx] : 0; sum += v[j]; }
    s[t] = sum; __syncthreads();
    for (int off = 1; off < 256; off <<= 1) {
        int x = (t >= off) ? s[t - off] : 0;
        __syncthreads();
        s[t] += x;
        __syncthreads();
    }
    int excl = (t > 0 ? s[t - 1] : 0) + boff[blockIdx.x];
#pragma unroll
    for (int j = 0; j < 4; j++) { int idx = base + t * 4 + j; if (idx < n) rowptr[idx] = excl; excl += v[j]; }
}

// atomic-free scatter: slot index precomputed in eord
__global__ __launch_bounds__(256) void k_scatter(const int* __restrict__ src,
                                                 const int* __restrict__ dst,
                                                 const float* __restrict__ w,
                                                 const float* __restrict__ dinv,
                                                 const int* __restrict__ rowptr,
                                                 const unsigned* __restrict__ eord,
                                                 int2* __restrict__ edges, int e) {
    for (int i = blockIdx.x * 256 + threadIdx.x; i < e; i += gridDim.x * 256) {
        int s = src[i], d = dst[i];
        int pos = rowptr[d] + (int)eord[i];
        float norm = dinv[s] * w[i] * dinv[d];
        edges[pos] = make_int2(s, __float_as_int(norm));
    }
}

// ---------------- GEMMs (wave per row, weights in registers) ----------------

__global__ __launch_bounds__(256) void k_gemm1(const float* __restrict__ x,
                                               const float* __restrict__ W1,
                                               float* __restrict__ h1, int n) {
    int lane = threadIdx.x & 63;
    int wid = threadIdx.x >> 6;
    float w[NFEAT];
#pragma unroll
    for (int k = 0; k < NFEAT; k++) w[k] = W1[k * HID + lane];
    int wave = blockIdx.x * 4 + wid;
    int nwaves = gridDim.x * 4;
    for (int row = wave; row < n; row += nwaves) {
        int r = __builtin_amdgcn_readfirstlane(row);
        const float4* xp = reinterpret_cast<const float4*>(x + (size_t)r * NFEAT);
        float acc = 0.f;
#pragma unroll
        for (int k0 = 0; k0 < NFEAT / 4; k0++) {
            float4 xv = xp[k0];
            acc = fmaf(xv.x, w[4 * k0 + 0], acc);
            acc = fmaf(xv.y, w[4 * k0 + 1], acc);
            acc = fmaf(xv.z, w[4 * k0 + 2], acc);
            acc = fmaf(xv.w, w[4 * k0 + 3], acc);
        }
        h1[(size_t)r * HID + lane] = acc;
    }
}

__global__ __launch_bounds__(256) void k_gemm2(const float* __restrict__ y,
                                               const float* __restrict__ W2,
                                               float* __restrict__ h2, int n) {
    int lane = threadIdx.x & 63;
    int wid = threadIdx.x >> 6;
    int c = lane < NCLS ? lane : 0;
    float w[HID];
#pragma unroll
    for (int k = 0; k < HID; k++) w[k] = W2[k * NCLS + c];
    int wave = blockIdx.x * 4 + wid;
    int nwaves = gridDim.x * 4;
    for (int row = wave; row < n; row += nwaves) {
        int r = __builtin_amdgcn_readfirstlane(row);
        const float4* yp = reinterpret_cast<const float4*>(y + (size_t)r * HID);
        float acc = 0.f;
#pragma unroll
        for (int k0 = 0; k0 < HID / 4; k0++) {
            float4 yv = yp[k0];
            acc = fmaf(yv.x, w[4 * k0 + 0], acc);
            acc = fmaf(yv.y, w[4 * k0 + 1], acc);
            acc = fmaf(yv.z, w[4 * k0 + 2], acc);
            acc = fmaf(yv.w, w[4 * k0 + 3], acc);
        }
        if (lane < NCLS) h2[(size_t)r * NCLS + lane] = acc;
    }
}

// ---------------- aggregations (wave per node, lane = feature, 4x unrolled) ----------------

__global__ __launch_bounds__(256) void k_agg1(const float* __restrict__ h1,
                                              const int* __restrict__ rowptr,
                                              const int2* __restrict__ edges,
                                              const float* __restrict__ dinv,
                                              const float* __restrict__ b1,
                                              float* __restrict__ y, int n) {
    int lane = threadIdx.x & 63;
    int wid = threadIdx.x >> 6;
    for (int node = blockIdx.x * 4 + wid; node < n; node += gridDim.x * 4) {
        int i = __builtin_amdgcn_readfirstlane(node);
        float di = dinv[i];
        float a0 = di * di * h1[(size_t)i * HID + lane];
        float a1 = 0.f, a2 = 0.f, a3 = 0.f;
        int s = rowptr[i], e = rowptr[i + 1];
        int p = s;
        for (; p + 4 <= e; p += 4) {
            int2 e0 = edges[p], e1 = edges[p + 1], e2 = edges[p + 2], e3 = edges[p + 3];
            a0 = fmaf(__int_as_float(e0.y), h1[(size_t)e0.x * HID + lane], a0);
            a1 = fmaf(__int_as_float(e1.y), h1[(size_t)e1.x * HID + lane], a1);
            a2 = fmaf(__int_as_float(e2.y), h1[(size_t)e2.x * HID + lane], a2);
            a3 = fmaf(__int_as_float(e3.y), h1[(size_t)e3.x * HID + lane], a3);
        }
        for (; p < e; p++) {
            int2 e0 = edges[p];
            a0 = fmaf(__int_as_float(e0.y), h1[(size_t)e0.x * HID + lane], a0);
        }
        float acc = (a0 + a1) + (a2 + a3) + b1[lane];
        y[(size_t)i * HID + lane] = fmaxf(acc, 0.f);
    }
}

__global__ __launch_bounds__(256) void k_agg2(const float* __restrict__ h2,
                                              const int* __restrict__ rowptr,
                                              const int2* __restrict__ edges,
                                              const float* __restrict__ dinv,
                                              const float* __restrict__ b2,
                                              float* __restrict__ out, int n) {
    int lane = threadIdx.x & 63;
    int wid = threadIdx.x >> 6;
    for (int node = blockIdx.x * 4 + wid; node < n; node += gridDim.x * 4) {
        int i = __builtin_amdgcn_readfirstlane(node);
        float di = dinv[i];
        int c = lane < NCLS ? lane : 0;
        float a0 = di * di * h2[(size_t)i * NCLS + c];
        float a1 = 0.f, a2 = 0.f, a3 = 0.f;
        int s = rowptr[i], e = rowptr[i + 1];
        int p = s;
        for (; p + 4 <= e; p += 4) {
            int2 e0 = edges[p], e1 = edges[p + 1], e2 = edges[p + 2], e3 = edges[p + 3];
            a0 = fmaf(__int_as_float(e0.y), h2[(size_t)e0.x * NCLS + c], a0);
            a1 = fmaf(__int_as_float(e1.y), h2[(size_t)e1.x * NCLS + c], a1);
            a2 = fmaf(__int_as_float(e2.y), h2[(size_t)e2.x * NCLS + c], a2);
            a3 = fmaf(__int_as_float(e3.y), h2[(size_t)e3.x * NCLS + c], a3);
        }
        for (; p < e; p++) {
            int2 e0 = edges[p];
            a0 = fmaf(__int_as_float(e0.y), h2[(size_t)e0.x * NCLS + c], a0);
        }
        float acc = (a0 + a1) + (a2 + a3) + b2[c];
        float z = lane < NCLS ? acc : -INFINITY;
        float m = z;
#pragma unroll
        for (int off = 32; off > 0; off >>= 1) m = fmaxf(m, __shfl_xor(m, off));
        float ex = lane < NCLS ? expf(z - m) : 0.f;
        float ssum = ex;
#pragma unroll
        for (int off = 32; off > 0; off >>= 1) ssum += __shfl_xor(ssum, off);
        if (lane < NCLS) out[(size_t)i * NCLS + lane] = z - m - logf(ssum);
    }
}

// ---------------- launch ----------------

extern "C" void kernel_launch(void* const* d_in, const int* in_sizes, int n_in,
                              void* d_out, int out_size, void* d_ws, size_t ws_size,
                              hipStream_t stream) {
    const float* x = (const float*)d_in[0];
    const int* edge_index = (const int*)d_in[1];
    const float* ew = (const float*)d_in[2];
    const float* W1 = (const float*)d_in[3];
    const float* b1 = (const float*)d_in[4];
    const float* W2 = (const float*)d_in[5];
    const float* b2 = (const float*)d_in[6];
    float* out = (float*)d_out;

    const int N = in_sizes[0] / NFEAT;      // 100000
    const int E = in_sizes[2];              // 1600000
    const int* src = edge_index;
    const int* dst = edge_index + E;

    // workspace layout (256B aligned, running offsets)
    char* ws = (char*)d_ws;
    size_t off = 0;
    auto alloc = [&](size_t bytes) { void* p = ws + off; off = (off + bytes + 255) & ~(size_t)255; return p; };
    unsigned long long* packed = (unsigned long long*)alloc((size_t)N * 8);
    float* dinv   = (float*)alloc((size_t)N * 4);
    int*   cnt    = (int*)alloc((size_t)N * 4);
    int*   rowptr = (int*)alloc((size_t)(N + 1) * 4);
    int*   bsum   = (int*)alloc(16384);
    int*   boff   = (int*)alloc(16384);
    unsigned* eord = (unsigned*)alloc((size_t)E * 4);
    int2*  edges  = (int2*)alloc((size_t)E * 8);
    float* h1     = (float*)alloc((size_t)N * HID * 4);
    float* y      = (float*)alloc((size_t)N * HID * 4);
    float* h2     = h1;                               // h1 dead after agg1

    const int nblkN = (N + 255) / 256;
    const int nblkScan = (N + 1023) / 1024;

    k_init<<<nblkN, 256, 0, stream>>>(packed, N);
    k_deg_cnt<<<2048, 256, 0, stream>>>(dst, ew, packed, eord, E);
    k_dinv<<<nblkN, 256, 0, stream>>>(packed, dinv, cnt, N);
    k_scan_partial<<<nblkScan, 256, 0, stream>>>(cnt, bsum, N);
    k_scan_blk<<<1, 64, 0, stream>>>(bsum, boff, rowptr, nblkScan, N);
    k_scan_final<<<nblkScan, 256, 0, stream>>>(cnt, boff, rowptr, N);
    k_scatter<<<2048, 256, 0, stream>>>(src, dst, ew, dinv, rowptr, eord, edges, E);
    k_gemm1<<<4096, 256, 0, stream>>>(x, W1, h1, N);
    k_agg1<<<(N + 3) / 4, 256, 0, stream>>>(h1, rowptr, edges, dinv, b1, y, N);
    k_gemm2<<<4096, 256, 0, stream>>>(y, W2, h2, N);
    k_agg2<<<(N + 3) / 4, 256, 0, stream>>>(h2, rowptr, edges, dinv, b2, out, N);
}

// Round 3
// 396.095 us; speedup vs baseline: 1.6734x; 1.1333x over previous
//
#include <hip/hip_runtime.h>
#include <hip/hip_bf16.h>
#include <math.h>

// GCN 2-layer: x[N,128] @ W1 -> agg -> relu -> @ W2 -> agg -> log_softmax
// N=100000, E=1600000, F=128, H=64, C=40

#define NFEAT 128
#define HID 64
#define NCLS 40

// deg+cnt packed in u64: high 32 = sum(w)*2^24 fixed point, low 32 = count.

__global__ __launch_bounds__(256) void k_init(unsigned long long* packed, int n) {
    int i = blockIdx.x * 256 + threadIdx.x;
    if (i < n) packed[i] = 1ull << 56;
}

__global__ __launch_bounds__(256) void k_deg_cnt(const int* __restrict__ dst,
                                                 const float* __restrict__ w,
                                                 unsigned long long* packed,
                                                 unsigned* __restrict__ eord, int e) {
    for (int i = blockIdx.x * 256 + threadIdx.x; i < e; i += gridDim.x * 256) {
        int d = dst[i];
        unsigned wq = (unsigned)(w[i] * 16777216.0f);
        unsigned long long inc = ((unsigned long long)wq << 32) | 1ull;
        unsigned long long old = atomicAdd(&packed[d], inc);
        eord[i] = (unsigned)(old & 0xffffffffull);   // slot within dst's row
    }
}

__global__ __launch_bounds__(256) void k_dinv(const unsigned long long* __restrict__ packed,
                                              float* dinv, int* cnt, int n) {
    int i = blockIdx.x * 256 + threadIdx.x;
    if (i < n) {
        unsigned long long p = packed[i];
        cnt[i] = (int)(p & 0xffffffffull);
        float deg = (float)(unsigned)(p >> 32) * (1.0f / 16777216.0f);
        dinv[i] = deg > 0.f ? rsqrtf(deg) : 0.f;
    }
}

// exclusive prefix scan of cnt[N] -> rowptr[N+1]
__global__ __launch_bounds__(256) void k_scan_partial(const int* __restrict__ cnt, int* bsum, int n) {
    __shared__ int s[256];
    int t = threadIdx.x;
    int base = blockIdx.x * 1024;
    int sum = 0;
#pragma unroll
    for (int j = 0; j < 4; j++) { int idx = base + t * 4 + j; sum += (idx < n) ? cnt[idx] : 0; }
    s[t] = sum; __syncthreads();
    for (int off = 128; off > 0; off >>= 1) { if (t < off) s[t] += s[t + off]; __syncthreads(); }
    if (t == 0) bsum[blockIdx.x] = s[0];
}

__global__ void k_scan_blk(const int* __restrict__ bsum, int* boff, int* rowptr, int nblk, int n) {
    if (threadIdx.x == 0 && blockIdx.x == 0) {
        int run = 0;
        for (int b = 0; b < nblk; b++) { boff[b] = run; run += bsum[b]; }
        rowptr[n] = run;
    }
}

__global__ __launch_bounds__(256) void k_scan_final(const int* __restrict__ cnt,
                                                    const int* __restrict__ boff,
                                                    int* rowptr, int n) {
    __shared__ int s[256];
    int t = threadIdx.x;
    int base = blockIdx.x * 1024;
    int v[4]; int sum = 0;
#pragma unroll
    for (int j = 0; j < 4; j++) { int idx = base + t * 4 + j; v[j] = (idx < n) ? cnt[idx] : 0; sum += v[j]; }
    s[t] = sum; __syncthreads();
    for (int off = 1; off < 256; off <<= 1) {
        int x = (t >= off) ? s[t - off] : 0;
        __syncthreads();
        s[t] += x;
        __syncthreads();
    }
    int excl = (t > 0 ? s[t - 1] : 0) + boff[blockIdx.x];
#pragma unroll
    for (int j = 0; j < 4; j++) { int idx = base + t * 4 + j; if (idx < n) rowptr[idx] = excl; excl += v[j]; }
}

// atomic-free scatter: slot index precomputed in eord
__global__ __launch_bounds__(256) void k_scatter(const int* __restrict__ src,
                                                 const int* __restrict__ dst,
                                                 const float* __restrict__ w,
                                                 const float* __restrict__ dinv,
                                                 const int* __restrict__ rowptr,
                                                 const unsigned* __restrict__ eord,
                                                 int2* __restrict__ edges, int e) {
    for (int i = blockIdx.x * 256 + threadIdx.x; i < e; i += gridDim.x * 256) {
        int s = src[i], d = dst[i];
        int pos = rowptr[d] + (int)eord[i];
        float norm = dinv[s] * w[i] * dinv[d];
        edges[pos] = make_int2(s, __float_as_int(norm));
    }
}

// ---------------- GEMMs: lane=row, wave=col-slice, x tile transposed in LDS ----------------
// Weights are wave-uniform loads (once per k per block) -> scalar path, L2-trivial.

__global__ __launch_bounds__(256) void k_gemm1(const float* __restrict__ x,
                                               const float* __restrict__ W1,
                                               float* __restrict__ h1, int n) {
    __shared__ float xs[NFEAT * 65];   // transposed [k][row], stride 65 (2-way bank on reads)
    int t = threadIdx.x;
    int lane = t & 63;
    int wid = __builtin_amdgcn_readfirstlane(t >> 6);
    int base = blockIdx.x * 64;
    int nrows = n - base; if (nrows > 64) nrows = 64;

    const float4* xg = reinterpret_cast<const float4*>(x + (size_t)base * NFEAT);
    for (int j = t; j < nrows * 32; j += 256) {
        int row = j >> 5, k4 = j & 31;
        float4 v = xg[j];
        xs[(4 * k4 + 0) * 65 + row] = v.x;
        xs[(4 * k4 + 1) * 65 + row] = v.y;
        xs[(4 * k4 + 2) * 65 + row] = v.z;
        xs[(4 * k4 + 3) * 65 + row] = v.w;
    }
    __syncthreads();

    const float* wb = W1 + wid * 16;
    float acc[16];
#pragma unroll
    for (int c = 0; c < 16; c++) acc[c] = 0.f;
#pragma unroll 4
    for (int k = 0; k < NFEAT; k++) {
        float xv = xs[k * 65 + lane];
        const float* wk = wb + k * HID;
#pragma unroll
        for (int c = 0; c < 16; c++) acc[c] = fmaf(wk[c], xv, acc[c]);
    }
    if (lane < nrows) {
        float4* hp = reinterpret_cast<float4*>(h1 + (size_t)(base + lane) * HID + wid * 16);
        hp[0] = make_float4(acc[0], acc[1], acc[2], acc[3]);
        hp[1] = make_float4(acc[4], acc[5], acc[6], acc[7]);
        hp[2] = make_float4(acc[8], acc[9], acc[10], acc[11]);
        hp[3] = make_float4(acc[12], acc[13], acc[14], acc[15]);
    }
}

__global__ __launch_bounds__(256) void k_gemm2(const float* __restrict__ y,
                                               const float* __restrict__ W2,
                                               float* __restrict__ h2, int n) {
    __shared__ float ys[HID * 65];     // transposed [k][row], stride 65
    int t = threadIdx.x;
    int lane = t & 63;
    int wid = __builtin_amdgcn_readfirstlane(t >> 6);
    int base = blockIdx.x * 64;
    int nrows = n - base; if (nrows > 64) nrows = 64;

    const float4* yg = reinterpret_cast<const float4*>(y + (size_t)base * HID);
    for (int j = t; j < nrows * 16; j += 256) {
        int row = j >> 4, k4 = j & 15;
        float4 v = yg[j];
        ys[(4 * k4 + 0) * 65 + row] = v.x;
        ys[(4 * k4 + 1) * 65 + row] = v.y;
        ys[(4 * k4 + 2) * 65 + row] = v.z;
        ys[(4 * k4 + 3) * 65 + row] = v.w;
    }
    __syncthreads();

    const float* wb = W2 + wid * 10;
    float acc[10];
#pragma unroll
    for (int c = 0; c < 10; c++) acc[c] = 0.f;
#pragma unroll 4
    for (int k = 0; k < HID; k++) {
        float yv = ys[k * 65 + lane];
        const float* wk = wb + k * NCLS;
#pragma unroll
        for (int c = 0; c < 10; c++) acc[c] = fmaf(wk[c], yv, acc[c]);
    }
    if (lane < nrows) {
        float2* hp = reinterpret_cast<float2*>(h2 + (size_t)(base + lane) * NCLS + wid * 10);
        hp[0] = make_float2(acc[0], acc[1]);
        hp[1] = make_float2(acc[2], acc[3]);
        hp[2] = make_float2(acc[4], acc[5]);
        hp[3] = make_float2(acc[6], acc[7]);
        hp[4] = make_float2(acc[8], acc[9]);
    }
}

// ---------------- aggregations (wave per node, lane = feature, 4x unrolled) ----------------

__global__ __launch_bounds__(256) void k_agg1(const float* __restrict__ h1,
                                              const int* __restrict__ rowptr,
                                              const int2* __restrict__ edges,
                                              const float* __restrict__ dinv,
                                              const float* __restrict__ b1,
                                              float* __restrict__ y, int n) {
    int lane = threadIdx.x & 63;
    int wid = threadIdx.x >> 6;
    for (int node = blockIdx.x * 4 + wid; node < n; node += gridDim.x * 4) {
        int i = __builtin_amdgcn_readfirstlane(node);
        float di = dinv[i];
        float a0 = di * di * h1[(size_t)i * HID + lane];
        float a1 = 0.f, a2 = 0.f, a3 = 0.f;
        int s = rowptr[i], e = rowptr[i + 1];
        int p = s;
        for (; p + 4 <= e; p += 4) {
            int2 e0 = edges[p], e1 = edges[p + 1], e2 = edges[p + 2], e3 = edges[p + 3];
            a0 = fmaf(__int_as_float(e0.y), h1[(size_t)e0.x * HID + lane], a0);
            a1 = fmaf(__int_as_float(e1.y), h1[(size_t)e1.x * HID + lane], a1);
            a2 = fmaf(__int_as_float(e2.y), h1[(size_t)e2.x * HID + lane], a2);
            a3 = fmaf(__int_as_float(e3.y), h1[(size_t)e3.x * HID + lane], a3);
        }
        for (; p < e; p++) {
            int2 e0 = edges[p];
            a0 = fmaf(__int_as_float(e0.y), h1[(size_t)e0.x * HID + lane], a0);
        }
        float acc = (a0 + a1) + (a2 + a3) + b1[lane];
        y[(size_t)i * HID + lane] = fmaxf(acc, 0.f);
    }
}

__global__ __launch_bounds__(256) void k_agg2(const float* __restrict__ h2,
                                              const int* __restrict__ rowptr,
                                              const int2* __restrict__ edges,
                                              const float* __restrict__ dinv,
                                              const float* __restrict__ b2,
                                              float* __restrict__ out, int n) {
    int lane = threadIdx.x & 63;
    int wid = threadIdx.x >> 6;
    for (int node = blockIdx.x * 4 + wid; node < n; node += gridDim.x * 4) {
        int i = __builtin_amdgcn_readfirstlane(node);
        float di = dinv[i];
        int c = lane < NCLS ? lane : 0;
        float a0 = di * di * h2[(size_t)i * NCLS + c];
        float a1 = 0.f, a2 = 0.f, a3 = 0.f;
        int s = rowptr[i], e = rowptr[i + 1];
        int p = s;
        for (; p + 4 <= e; p += 4) {
            int2 e0 = edges[p], e1 = edges[p + 1], e2 = edges[p + 2], e3 = edges[p + 3];
            a0 = fmaf(__int_as_float(e0.y), h2[(size_t)e0.x * NCLS + c], a0);
            a1 = fmaf(__int_as_float(e1.y), h2[(size_t)e1.x * NCLS + c], a1);
            a2 = fmaf(__int_as_float(e2.y), h2[(size_t)e2.x * NCLS + c], a2);
            a3 = fmaf(__int_as_float(e3.y), h2[(size_t)e3.x * NCLS + c], a3);
        }
        for (; p < e; p++) {
            int2 e0 = edges[p];
            a0 = fmaf(__int_as_float(e0.y), h2[(size_t)e0.x * NCLS + c], a0);
        }
        float acc = (a0 + a1) + (a2 + a3) + b2[c];
        float z = lane < NCLS ? acc : -INFINITY;
        float m = z;
#pragma unroll
        for (int off = 32; off > 0; off >>= 1) m = fmaxf(m, __shfl_xor(m, off));
        float ex = lane < NCLS ? expf(z - m) : 0.f;
        float ssum = ex;
#pragma unroll
        for (int off = 32; off > 0; off >>= 1) ssum += __shfl_xor(ssum, off);
        if (lane < NCLS) out[(size_t)i * NCLS + lane] = z - m - logf(ssum);
    }
}

// ---------------- launch ----------------

extern "C" void kernel_launch(void* const* d_in, const int* in_sizes, int n_in,
                              void* d_out, int out_size, void* d_ws, size_t ws_size,
                              hipStream_t stream) {
    const float* x = (const float*)d_in[0];
    const int* edge_index = (const int*)d_in[1];
    const float* ew = (const float*)d_in[2];
    const float* W1 = (const float*)d_in[3];
    const float* b1 = (const float*)d_in[4];
    const float* W2 = (const float*)d_in[5];
    const float* b2 = (const float*)d_in[6];
    float* out = (float*)d_out;

    const int N = in_sizes[0] / NFEAT;      // 100000
    const int E = in_sizes[2];              // 1600000
    const int* src = edge_index;
    const int* dst = edge_index + E;

    char* ws = (char*)d_ws;
    size_t off = 0;
    auto alloc = [&](size_t bytes) { void* p = ws + off; off = (off + bytes + 255) & ~(size_t)255; return p; };
    unsigned long long* packed = (unsigned long long*)alloc((size_t)N * 8);
    float* dinv   = (float*)alloc((size_t)N * 4);
    int*   cnt    = (int*)alloc((size_t)N * 4);
    int*   rowptr = (int*)alloc((size_t)(N + 1) * 4);
    int*   bsum   = (int*)alloc(16384);
    int*   boff   = (int*)alloc(16384);
    unsigned* eord = (unsigned*)alloc((size_t)E * 4);
    int2*  edges  = (int2*)alloc((size_t)E * 8);
    float* h1     = (float*)alloc((size_t)N * HID * 4);
    float* y      = (float*)alloc((size_t)N * HID * 4);
    float* h2     = h1;                               // h1 dead after agg1

    const int nblkN = (N + 255) / 256;
    const int nblkScan = (N + 1023) / 1024;
    const int nblkTile = (N + 63) / 64;

    k_init<<<nblkN, 256, 0, stream>>>(packed, N);
    k_deg_cnt<<<2048, 256, 0, stream>>>(dst, ew, packed, eord, E);
    k_dinv<<<nblkN, 256, 0, stream>>>(packed, dinv, cnt, N);
    k_scan_partial<<<nblkScan, 256, 0, stream>>>(cnt, bsum, N);
    k_scan_blk<<<1, 64, 0, stream>>>(bsum, boff, rowptr, nblkScan, N);
    k_scan_final<<<nblkScan, 256, 0, stream>>>(cnt, boff, rowptr, N);
    k_scatter<<<2048, 256, 0, stream>>>(src, dst, ew, dinv, rowptr, eord, edges, E);
    k_gemm1<<<nblkTile, 256, 0, stream>>>(x, W1, h1, N);
    k_agg1<<<(N + 3) / 4, 256, 0, stream>>>(h1, rowptr, edges, dinv, b1, y, N);
    k_gemm2<<<nblkTile, 256, 0, stream>>>(y, W2, h2, N);
    k_agg2<<<(N + 3) / 4, 256, 0, stream>>>(h2, rowptr, edges, dinv, b2, out, N);
}

// Round 5
// 393.769 us; speedup vs baseline: 1.6833x; 1.0059x over previous
//
#include <hip/hip_runtime.h>
#include <hip/hip_bf16.h>
#include <math.h>

// GCN 2-layer: x[N,128] @ W1 -> agg -> relu -> @ W2 -> agg -> log_softmax
// N=100000, E=1600000, F=128, H=64, C=40

#define NFEAT 128
#define HID 64
#define NCLS 40
#define DEGB 800   // deg blocks in fused kernel; 800*256*8 >= E

// deg+cnt packed in u64: high 32 = sum(w)*2^24 fixed point, low 32 = count.

__global__ __launch_bounds__(256) void k_init(unsigned long long* packed, int n) {
    int i = blockIdx.x * 256 + threadIdx.x;
    if (i < n) packed[i] = 1ull << 56;
}

// Fused: blocks [0,DEGB) = deg/cnt atomics (8 batched per thread);
//        blocks [DEGB, DEGB+ceil(n/64)) = gemm1 64-row tiles.
__global__ __launch_bounds__(256) void k_fused_deg_gemm1(
        const int* __restrict__ dst, const float* __restrict__ w,
        unsigned long long* packed, unsigned* __restrict__ eord, int e,
        const float* __restrict__ x, const float* __restrict__ W1,
        float* __restrict__ h1, int n) {
    __shared__ float xs[64 * 65];
    int t = threadIdx.x;
    if (blockIdx.x < DEGB) {
        // ---- deg path: 8 independent atomics in flight per thread ----
        const int T = DEGB * 256;
        int tid = blockIdx.x * 256 + t;
        int d[8]; unsigned long long inc[8]; unsigned long long old[8];
#pragma unroll
        for (int j = 0; j < 8; j++) {
            int i = tid + j * T;
            if (i < e) {
                d[j] = dst[i];
                unsigned wq = (unsigned)(w[i] * 16777216.0f);
                inc[j] = ((unsigned long long)wq << 32) | 1ull;
            } else d[j] = -1;
        }
#pragma unroll
        for (int j = 0; j < 8; j++)
            if (d[j] >= 0) old[j] = atomicAdd(&packed[d[j]], inc[j]);
#pragma unroll
        for (int j = 0; j < 8; j++) {
            int i = tid + j * T;
            if (d[j] >= 0) eord[i] = (unsigned)(old[j] & 0xffffffffull);
        }
    } else {
        // ---- gemm1 path: 64 rows, K split in two 64-wide halves ----
        int lane = t & 63;
        int wid = __builtin_amdgcn_readfirstlane(t >> 6);
        int base = (blockIdx.x - DEGB) * 64;
        int nrows = n - base; if (nrows > 64) nrows = 64;
        const float4* xg = reinterpret_cast<const float4*>(x + (size_t)base * NFEAT);
        float acc[16];
#pragma unroll
        for (int c = 0; c < 16; c++) acc[c] = 0.f;
#pragma unroll
        for (int h = 0; h < 2; h++) {
            for (int j = t; j < nrows * 16; j += 256) {
                int row = j >> 4, k4 = j & 15;
                float4 v = xg[row * 32 + h * 16 + k4];
                xs[(4 * k4 + 0) * 65 + row] = v.x;
                xs[(4 * k4 + 1) * 65 + row] = v.y;
                xs[(4 * k4 + 2) * 65 + row] = v.z;
                xs[(4 * k4 + 3) * 65 + row] = v.w;
            }
            __syncthreads();
            const float* wb = W1 + (size_t)(h * 64) * HID + wid * 16;
#pragma unroll 4
            for (int k = 0; k < 64; k++) {
                float xv = xs[k * 65 + lane];
                const float* wk = wb + k * HID;
#pragma unroll
                for (int c = 0; c < 16; c++) acc[c] = fmaf(wk[c], xv, acc[c]);
            }
            __syncthreads();
        }
        if (lane < nrows) {
            float4* hp = reinterpret_cast<float4*>(h1 + (size_t)(base + lane) * HID + wid * 16);
            hp[0] = make_float4(acc[0], acc[1], acc[2], acc[3]);
            hp[1] = make_float4(acc[4], acc[5], acc[6], acc[7]);
            hp[2] = make_float4(acc[8], acc[9], acc[10], acc[11]);
            hp[3] = make_float4(acc[12], acc[13], acc[14], acc[15]);
        }
    }
}

// dinv + scan partial sums fused; cnt read from packed low32
__global__ __launch_bounds__(256) void k_dinv_scan_partial(
        const unsigned long long* __restrict__ packed,
        float* __restrict__ dinv, int* bsum, int n) {
    __shared__ int s[256];
    int t = threadIdx.x;
    int base = blockIdx.x * 1024;
    int sum = 0;
#pragma unroll
    for (int j = 0; j < 4; j++) {
        int idx = base + t * 4 + j;
        if (idx < n) {
            unsigned long long p = packed[idx];
            sum += (int)(p & 0xffffffffull);
            float deg = (float)(unsigned)(p >> 32) * (1.0f / 16777216.0f);
            dinv[idx] = deg > 0.f ? rsqrtf(deg) : 0.f;
        }
    }
    s[t] = sum; __syncthreads();
    for (int off = 128; off > 0; off >>= 1) { if (t < off) s[t] += s[t + off]; __syncthreads(); }
    if (t == 0) bsum[blockIdx.x] = s[0];
}

__global__ void k_scan_blk(const int* __restrict__ bsum, int* boff, int* rowptr, int nblk, int n) {
    if (threadIdx.x == 0 && blockIdx.x == 0) {
        int run = 0;
        for (int b = 0; b < nblk; b++) { boff[b] = run; run += bsum[b]; }
        rowptr[n] = run;
    }
}

__global__ __launch_bounds__(256) void k_scan_final(const unsigned long long* __restrict__ packed,
                                                    const int* __restrict__ boff,
                                                    int* rowptr, int n) {
    __shared__ int s[256];
    int t = threadIdx.x;
    int base = blockIdx.x * 1024;
    int v[4]; int sum = 0;
#pragma unroll
    for (int j = 0; j < 4; j++) {
        int idx = base + t * 4 + j;
        v[j] = (idx < n) ? (int)(packed[idx] & 0xffffffffull) : 0;
        sum += v[j];
    }
    s[t] = sum; __syncthreads();
    for (int off = 1; off < 256; off <<= 1) {
        int x = (t >= off) ? s[t - off] : 0;
        __syncthreads();
        s[t] += x;
        __syncthreads();
    }
    int excl = (t > 0 ? s[t - 1] : 0) + boff[blockIdx.x];
#pragma unroll
    for (int j = 0; j < 4; j++) { int idx = base + t * 4 + j; if (idx < n) rowptr[idx] = excl; excl += v[j]; }
}

// atomic-free scatter: slot index precomputed in eord
__global__ __launch_bounds__(256) void k_scatter(const int* __restrict__ src,
                                                 const int* __restrict__ dst,
                                                 const float* __restrict__ w,
                                                 const float* __restrict__ dinv,
                                                 const int* __restrict__ rowptr,
                                                 const unsigned* __restrict__ eord,
                                                 int2* __restrict__ edges, int e) {
    for (int i = blockIdx.x * 256 + threadIdx.x; i < e; i += gridDim.x * 256) {
        int s = src[i], d = dst[i];
        int pos = rowptr[d] + (int)eord[i];
        float norm = dinv[s] * w[i] * dinv[d];
        edges[pos] = make_int2(s, __float_as_int(norm));
    }
}

__global__ __launch_bounds__(256) void k_gemm2(const float* __restrict__ y,
                                               const float* __restrict__ W2,
                                               float* __restrict__ h2, int n) {
    __shared__ float ys[HID * 65];
    int t = threadIdx.x;
    int lane = t & 63;
    int wid = __builtin_amdgcn_readfirstlane(t >> 6);
    int base = blockIdx.x * 64;
    int nrows = n - base; if (nrows > 64) nrows = 64;

    const float4* yg = reinterpret_cast<const float4*>(y + (size_t)base * HID);
    for (int j = t; j < nrows * 16; j += 256) {
        int row = j >> 4, k4 = j & 15;
        float4 v = yg[j];
        ys[(4 * k4 + 0) * 65 + row] = v.x;
        ys[(4 * k4 + 1) * 65 + row] = v.y;
        ys[(4 * k4 + 2) * 65 + row] = v.z;
        ys[(4 * k4 + 3) * 65 + row] = v.w;
    }
    __syncthreads();

    const float* wb = W2 + wid * 10;
    float acc[10];
#pragma unroll
    for (int c = 0; c < 10; c++) acc[c] = 0.f;
#pragma unroll 4
    for (int k = 0; k < HID; k++) {
        float yv = ys[k * 65 + lane];
        const float* wk = wb + k * NCLS;
#pragma unroll
        for (int c = 0; c < 10; c++) acc[c] = fmaf(wk[c], yv, acc[c]);
    }
    if (lane < nrows) {
        float2* hp = reinterpret_cast<float2*>(h2 + (size_t)(base + lane) * NCLS + wid * 10);
        hp[0] = make_float2(acc[0], acc[1]);
        hp[1] = make_float2(acc[2], acc[3]);
        hp[2] = make_float2(acc[4], acc[5]);
        hp[3] = make_float2(acc[6], acc[7]);
        hp[4] = make_float2(acc[8], acc[9]);
    }
}

// ---------------- aggregations (wave per node, lane = feature, 8x unrolled) ----------------

__global__ __launch_bounds__(256) void k_agg1(const float* __restrict__ h1,
                                              const int* __restrict__ rowptr,
                                              const int2* __restrict__ edges,
                                              const float* __restrict__ dinv,
                                              const float* __restrict__ b1,
                                              float* __restrict__ y, int n) {
    int lane = threadIdx.x & 63;
    int wid = threadIdx.x >> 6;
    for (int node = blockIdx.x * 4 + wid; node < n; node += gridDim.x * 4) {
        int i = __builtin_amdgcn_readfirstlane(node);
        float di = dinv[i];
        float a0 = di * di * h1[(size_t)i * HID + lane];
        float a1 = 0.f, a2 = 0.f, a3 = 0.f, a4 = 0.f, a5 = 0.f, a6 = 0.f, a7 = 0.f;
        int s = rowptr[i], e = rowptr[i + 1];
        int p = s;
        for (; p + 8 <= e; p += 8) {
            int2 e0 = edges[p], e1 = edges[p + 1], e2 = edges[p + 2], e3 = edges[p + 3];
            int2 e4 = edges[p + 4], e5 = edges[p + 5], e6 = edges[p + 6], e7 = edges[p + 7];
            a0 = fmaf(__int_as_float(e0.y), h1[(size_t)e0.x * HID + lane], a0);
            a1 = fmaf(__int_as_float(e1.y), h1[(size_t)e1.x * HID + lane], a1);
            a2 = fmaf(__int_as_float(e2.y), h1[(size_t)e2.x * HID + lane], a2);
            a3 = fmaf(__int_as_float(e3.y), h1[(size_t)e3.x * HID + lane], a3);
            a4 = fmaf(__int_as_float(e4.y), h1[(size_t)e4.x * HID + lane], a4);
            a5 = fmaf(__int_as_float(e5.y), h1[(size_t)e5.x * HID + lane], a5);
            a6 = fmaf(__int_as_float(e6.y), h1[(size_t)e6.x * HID + lane], a6);
            a7 = fmaf(__int_as_float(e7.y), h1[(size_t)e7.x * HID + lane], a7);
        }
        for (; p + 4 <= e; p += 4) {
            int2 e0 = edges[p], e1 = edges[p + 1], e2 = edges[p + 2], e3 = edges[p + 3];
            a0 = fmaf(__int_as_float(e0.y), h1[(size_t)e0.x * HID + lane], a0);
            a1 = fmaf(__int_as_float(e1.y), h1[(size_t)e1.x * HID + lane], a1);
            a2 = fmaf(__int_as_float(e2.y), h1[(size_t)e2.x * HID + lane], a2);
            a3 = fmaf(__int_as_float(e3.y), h1[(size_t)e3.x * HID + lane], a3);
        }
        for (; p < e; p++) {
            int2 e0 = edges[p];
            a0 = fmaf(__int_as_float(e0.y), h1[(size_t)e0.x * HID + lane], a0);
        }
        float acc = ((a0 + a1) + (a2 + a3)) + ((a4 + a5) + (a6 + a7)) + b1[lane];
        y[(size_t)i * HID + lane] = fmaxf(acc, 0.f);
    }
}

__global__ __launch_bounds__(256) void k_agg2(const float* __restrict__ h2,
                                              const int* __restrict__ rowptr,
                                              const int2* __restrict__ edges,
                                              const float* __restrict__ dinv,
                                              const float* __restrict__ b2,
                                              float* __restrict__ out, int n) {
    int lane = threadIdx.x & 63;
    int wid = threadIdx.x >> 6;
    for (int node = blockIdx.x * 4 + wid; node < n; node += gridDim.x * 4) {
        int i = __builtin_amdgcn_readfirstlane(node);
        float di = dinv[i];
        int c = lane < NCLS ? lane : 0;
        float a0 = di * di * h2[(size_t)i * NCLS + c];
        float a1 = 0.f, a2 = 0.f, a3 = 0.f, a4 = 0.f, a5 = 0.f, a6 = 0.f, a7 = 0.f;
        int s = rowptr[i], e = rowptr[i + 1];
        int p = s;
        for (; p + 8 <= e; p += 8) {
            int2 e0 = edges[p], e1 = edges[p + 1], e2 = edges[p + 2], e3 = edges[p + 3];
            int2 e4 = edges[p + 4], e5 = edges[p + 5], e6 = edges[p + 6], e7 = edges[p + 7];
            a0 = fmaf(__int_as_float(e0.y), h2[(size_t)e0.x * NCLS + c], a0);
            a1 = fmaf(__int_as_float(e1.y), h2[(size_t)e1.x * NCLS + c], a1);
            a2 = fmaf(__int_as_float(e2.y), h2[(size_t)e2.x * NCLS + c], a2);
            a3 = fmaf(__int_as_float(e3.y), h2[(size_t)e3.x * NCLS + c], a3);
            a4 = fmaf(__int_as_float(e4.y), h2[(size_t)e4.x * NCLS + c], a4);
            a5 = fmaf(__int_as_float(e5.y), h2[(size_t)e5.x * NCLS + c], a5);
            a6 = fmaf(__int_as_float(e6.y), h2[(size_t)e6.x * NCLS + c], a6);
            a7 = fmaf(__int_as_float(e7.y), h2[(size_t)e7.x * NCLS + c], a7);
        }
        for (; p + 4 <= e; p += 4) {
            int2 e0 = edges[p], e1 = edges[p + 1], e2 = edges[p + 2], e3 = edges[p + 3];
            a0 = fmaf(__int_as_float(e0.y), h2[(size_t)e0.x * NCLS + c], a0);
            a1 = fmaf(__int_as_float(e1.y), h2[(size_t)e1.x * NCLS + c], a1);
            a2 = fmaf(__int_as_float(e2.y), h2[(size_t)e2.x * NCLS + c], a2);
            a3 = fmaf(__int_as_float(e3.y), h2[(size_t)e3.x * NCLS + c], a3);
        }
        for (; p < e; p++) {
            int2 e0 = edges[p];
            a0 = fmaf(__int_as_float(e0.y), h2[(size_t)e0.x * NCLS + c], a0);
        }
        float acc = ((a0 + a1) + (a2 + a3)) + ((a4 + a5) + (a6 + a7)) + b2[c];
        float z = lane < NCLS ? acc : -INFINITY;
        float m = z;
#pragma unroll
        for (int off = 32; off > 0; off >>= 1) m = fmaxf(m, __shfl_xor(m, off));
        float ex = lane < NCLS ? expf(z - m) : 0.f;
        float ssum = ex;
#pragma unroll
        for (int off = 32; off > 0; off >>= 1) ssum += __shfl_xor(ssum, off);
        if (lane < NCLS) out[(size_t)i * NCLS + lane] = z - m - logf(ssum);
    }
}

// ---------------- launch ----------------

extern "C" void kernel_launch(void* const* d_in, const int* in_sizes, int n_in,
                              void* d_out, int out_size, void* d_ws, size_t ws_size,
                              hipStream_t stream) {
    const float* x = (const float*)d_in[0];
    const int* edge_index = (const int*)d_in[1];
    const float* ew = (const float*)d_in[2];
    const float* W1 = (const float*)d_in[3];
    const float* b1 = (const float*)d_in[4];
    const float* W2 = (const float*)d_in[5];
    const float* b2 = (const float*)d_in[6];
    float* out = (float*)d_out;

    const int N = in_sizes[0] / NFEAT;      // 100000
    const int E = in_sizes[2];              // 1600000
    const int* src = edge_index;
    const int* dst = edge_index + E;

    char* ws = (char*)d_ws;
    size_t off = 0;
    auto alloc = [&](size_t bytes) { void* p = ws + off; off = (off + bytes + 255) & ~(size_t)255; return p; };
    unsigned long long* packed = (unsigned long long*)alloc((size_t)N * 8);
    float* dinv   = (float*)alloc((size_t)N * 4);
    int*   rowptr = (int*)alloc((size_t)(N + 1) * 4);
    int*   bsum   = (int*)alloc(16384);
    int*   boff   = (int*)alloc(16384);
    unsigned* eord = (unsigned*)alloc((size_t)E * 4);
    int2*  edges  = (int2*)alloc((size_t)E * 8);
    float* h1     = (float*)alloc((size_t)N * HID * 4);
    float* y      = (float*)alloc((size_t)N * HID * 4);
    float* h2     = h1;                               // h1 dead after agg1

    const int nblkN = (N + 255) / 256;
    const int nblkScan = (N + 1023) / 1024;
    const int nblkTile = (N + 63) / 64;

    k_init<<<nblkN, 256, 0, stream>>>(packed, N);
    k_fused_deg_gemm1<<<DEGB + nblkTile, 256, 0, stream>>>(dst, ew, packed, eord, E,
                                                           x, W1, h1, N);
    k_dinv_scan_partial<<<nblkScan, 256, 0, stream>>>(packed, dinv, bsum, N);
    k_scan_blk<<<1, 64, 0, stream>>>(bsum, boff, rowptr, nblkScan, N);
    k_scan_final<<<nblkScan, 256, 0, stream>>>(packed, boff, rowptr, N);
    k_scatter<<<2048, 256, 0, stream>>>(src, dst, ew, dinv, rowptr, eord, edges, E);
    k_agg1<<<(N + 3) / 4, 256, 0, stream>>>(h1, rowptr, edges, dinv, b1, y, N);
    k_gemm2<<<nblkTile, 256, 0, stream>>>(y, W2, h2, N);
    k_agg2<<<(N + 3) / 4, 256, 0, stream>>>(h2, rowptr, edges, dinv, b2, out, N);
}

// Round 6
// 335.748 us; speedup vs baseline: 1.9742x; 1.1728x over previous
//
#include <hip/hip_runtime.h>
#include <hip/hip_bf16.h>
#include <math.h>

// GCN 2-layer: x[N,128] @ W1 -> agg -> relu -> @ W2 -> agg -> log_softmax
// N=100000, E=1600000, F=128, H=64, C=40
// CSR built via LDS bucket counting-sort: ZERO global atomics (far-atomic
// ceiling ~23 G/s made the atomic build a 70+ us floor).

#define NFEAT 128
#define HID 64
#define NCLS 40
#define PB 512          // partition blocks for hist/bucketize
#define BSH 7           // 128 nodes per bucket
#define NBUK_MAX 1024

// ---------- Pass A: per-block bucket histogram ----------
__global__ __launch_bounds__(256) void k_hist(const int* __restrict__ dst,
                                              int* __restrict__ ghist,
                                              int e, int nbuk, int epb) {
    __shared__ int hist[NBUK_MAX];
    for (int j = threadIdx.x; j < nbuk; j += 256) hist[j] = 0;
    __syncthreads();
    int b = blockIdx.x;
    int lo = b * epb, hi = min(lo + epb, e);
    for (int i = lo + threadIdx.x; i < hi; i += 256)
        atomicAdd(&hist[dst[i] >> BSH], 1);
    __syncthreads();
    for (int j = threadIdx.x; j < nbuk; j += 256) ghist[j * PB + b] = hist[j];
}

// ---------- Pass B1: exclusive scan of each bucket's column (in place) ----------
__global__ __launch_bounds__(256) void k_colscan(int* __restrict__ ghist,
                                                 int* __restrict__ buktot, int nbuk) {
    __shared__ int s[256];
    int k = blockIdx.x, t = threadIdx.x;
    int* col = ghist + k * PB;
    int v0 = col[2 * t], v1 = col[2 * t + 1];
    int sum = v0 + v1;
    s[t] = sum; __syncthreads();
    for (int off = 1; off < 256; off <<= 1) {
        int x = (t >= off) ? s[t - off] : 0;
        __syncthreads();
        s[t] += x;
        __syncthreads();
    }
    int excl = s[t] - sum;
    col[2 * t] = excl;
    col[2 * t + 1] = excl + v0;
    if (t == 255) buktot[k] = s[255];
}

// ---------- Pass B2: scan bucket totals -> bukstart; also rowptr[n]=e ----------
__global__ __launch_bounds__(256) void k_bukscan(const int* __restrict__ buktot,
                                                 int* __restrict__ bukstart,
                                                 int* __restrict__ rowptr,
                                                 int nbuk, int n, int e) {
    __shared__ int s[256];
    int t = threadIdx.x;
    int v[4]; int sum = 0;
#pragma unroll
    for (int j = 0; j < 4; j++) { int idx = t * 4 + j; v[j] = (idx < nbuk) ? buktot[idx] : 0; sum += v[j]; }
    s[t] = sum; __syncthreads();
    for (int off = 1; off < 256; off <<= 1) {
        int x = (t >= off) ? s[t - off] : 0;
        __syncthreads();
        s[t] += x;
        __syncthreads();
    }
    int excl = s[t] - sum;
#pragma unroll
    for (int j = 0; j < 4; j++) { int idx = t * 4 + j; if (idx < nbuk) bukstart[idx] = excl; excl += v[j]; }
    if (t == 255) bukstart[nbuk] = s[255];
    if (t == 0) rowptr[n] = e;
}

// ---------- Pass C: scatter edges into bucket-sorted order (LDS atomics only) ----------
__global__ __launch_bounds__(256) void k_bucketize(const int* __restrict__ src,
                                                   const int* __restrict__ dst,
                                                   const float* __restrict__ w,
                                                   const int* __restrict__ ghist,
                                                   const int* __restrict__ bukstart,
                                                   unsigned long long* __restrict__ sedge,
                                                   int e, int nbuk, int epb) {
    __shared__ int loff[NBUK_MAX];
    int b = blockIdx.x;
    for (int j = threadIdx.x; j < nbuk; j += 256) loff[j] = bukstart[j] + ghist[j * PB + b];
    __syncthreads();
    int lo = b * epb, hi = min(lo + epb, e);
    for (int i = lo + threadIdx.x; i < hi; i += 256) {
        int d = dst[i], s = src[i];
        int k = d >> BSH;
        int pos = atomicAdd(&loff[k], 1);
        unsigned long long rec = ((unsigned long long)__float_as_uint(w[i]) << 32)
                               | ((unsigned)(d & 127) << 17) | (unsigned)s;
        sedge[pos] = rec;
    }
}

// ---------- Pass D: per-bucket CSR + degree (LDS float adds) ----------
__global__ __launch_bounds__(256) void k_bucket_csr(const unsigned long long* __restrict__ sedge,
                                                    const int* __restrict__ bukstart,
                                                    int* __restrict__ rowptr,
                                                    float* __restrict__ dinv,
                                                    int2* __restrict__ edges, int n) {
    __shared__ int cnt[128]; __shared__ float wsum[128];
    __shared__ int fill[128]; __shared__ int rloc[128];
    int k = blockIdx.x, t = threadIdx.x;
    int base = k << BSH;
    int nloc = n - base; if (nloc > 128) nloc = 128;
    if (t < 128) { cnt[t] = 0; fill[t] = 0; wsum[t] = 1.0f; }   // 1.0 = self-loop weight
    __syncthreads();
    int lo = bukstart[k], hi = bukstart[k + 1];
    for (int p = lo + t; p < hi; p += 256) {
        unsigned long long r = sedge[p];
        int dloc = (int)((r >> 17) & 127);
        atomicAdd(&cnt[dloc], 1);
        atomicAdd(&wsum[dloc], __uint_as_float((unsigned)(r >> 32)));
    }
    __syncthreads();
    if (t < 128) rloc[t] = cnt[t];
    __syncthreads();
    for (int off = 1; off < 128; off <<= 1) {
        int x = 0;
        if (t < 128 && t >= off) x = rloc[t - off];
        __syncthreads();
        if (t < 128) rloc[t] += x;
        __syncthreads();
    }
    if (t < 128) {
        int excl = rloc[t] - cnt[t];
        rloc[t] = excl;
        if (t < nloc) {
            rowptr[base + t] = lo + excl;
            dinv[base + t] = rsqrtf(wsum[t]);   // deg >= 1 (self loop)
        }
    }
    __syncthreads();
    for (int p = lo + t; p < hi; p += 256) {
        unsigned long long r = sedge[p];
        int dloc = (int)((r >> 17) & 127);
        int srcn = (int)(r & 0x1ffff);
        int pos = lo + rloc[dloc] + atomicAdd(&fill[dloc], 1);
        edges[pos] = make_int2((dloc << 17) | srcn, (int)(unsigned)(r >> 32)); // keep dloc+raw w
    }
}

// ---------- Pass E: normalize edge values in place ----------
__global__ __launch_bounds__(256) void k_norm(const int* __restrict__ bukstart,
                                              const float* __restrict__ dinv,
                                              int2* __restrict__ edges, int n) {
    int k = blockIdx.x;
    int base = k << BSH;
    int lo = bukstart[k], hi = bukstart[k + 1];
    for (int p = lo + threadIdx.x; p < hi; p += 256) {
        int2 rec = edges[p];
        int dloc = rec.x >> 17, srcn = rec.x & 0x1ffff;
        float v = __int_as_float(rec.y) * dinv[srcn] * dinv[base + dloc];
        edges[p] = make_int2(srcn, __float_as_int(v));
    }
}

// ---------- GEMM1: 64-row tiles, x transposed in LDS, wave-uniform weights ----------
__global__ __launch_bounds__(256) void k_gemm1(const float* __restrict__ x,
                                               const float* __restrict__ W1,
                                               float* __restrict__ h1, int n) {
    __shared__ float xs[64 * 65];
    int t = threadIdx.x;
    int lane = t & 63;
    int wid = __builtin_amdgcn_readfirstlane(t >> 6);
    int base = blockIdx.x * 64;
    int nrows = n - base; if (nrows > 64) nrows = 64;
    const float4* xg = reinterpret_cast<const float4*>(x + (size_t)base * NFEAT);
    float acc[16];
#pragma unroll
    for (int c = 0; c < 16; c++) acc[c] = 0.f;
#pragma unroll
    for (int h = 0; h < 2; h++) {
        for (int j = t; j < nrows * 16; j += 256) {
            int row = j >> 4, k4 = j & 15;
            float4 v = xg[row * 32 + h * 16 + k4];
            xs[(4 * k4 + 0) * 65 + row] = v.x;
            xs[(4 * k4 + 1) * 65 + row] = v.y;
            xs[(4 * k4 + 2) * 65 + row] = v.z;
            xs[(4 * k4 + 3) * 65 + row] = v.w;
        }
        __syncthreads();
        const float* wb = W1 + (size_t)(h * 64) * HID + wid * 16;
#pragma unroll 4
        for (int k = 0; k < 64; k++) {
            float xv = xs[k * 65 + lane];
            const float* wk = wb + k * HID;
#pragma unroll
            for (int c = 0; c < 16; c++) acc[c] = fmaf(wk[c], xv, acc[c]);
        }
        __syncthreads();
    }
    if (lane < nrows) {
        float4* hp = reinterpret_cast<float4*>(h1 + (size_t)(base + lane) * HID + wid * 16);
        hp[0] = make_float4(acc[0], acc[1], acc[2], acc[3]);
        hp[1] = make_float4(acc[4], acc[5], acc[6], acc[7]);
        hp[2] = make_float4(acc[8], acc[9], acc[10], acc[11]);
        hp[3] = make_float4(acc[12], acc[13], acc[14], acc[15]);
    }
}

__global__ __launch_bounds__(256) void k_gemm2(const float* __restrict__ y,
                                               const float* __restrict__ W2,
                                               float* __restrict__ h2, int n) {
    __shared__ float ys[HID * 65];
    int t = threadIdx.x;
    int lane = t & 63;
    int wid = __builtin_amdgcn_readfirstlane(t >> 6);
    int base = blockIdx.x * 64;
    int nrows = n - base; if (nrows > 64) nrows = 64;
    const float4* yg = reinterpret_cast<const float4*>(y + (size_t)base * HID);
    for (int j = t; j < nrows * 16; j += 256) {
        int row = j >> 4, k4 = j & 15;
        float4 v = yg[j];
        ys[(4 * k4 + 0) * 65 + row] = v.x;
        ys[(4 * k4 + 1) * 65 + row] = v.y;
        ys[(4 * k4 + 2) * 65 + row] = v.z;
        ys[(4 * k4 + 3) * 65 + row] = v.w;
    }
    __syncthreads();
    const float* wb = W2 + wid * 10;
    float acc[10];
#pragma unroll
    for (int c = 0; c < 10; c++) acc[c] = 0.f;
#pragma unroll 4
    for (int k = 0; k < HID; k++) {
        float yv = ys[k * 65 + lane];
        const float* wk = wb + k * NCLS;
#pragma unroll
        for (int c = 0; c < 10; c++) acc[c] = fmaf(wk[c], yv, acc[c]);
    }
    if (lane < nrows) {
        float2* hp = reinterpret_cast<float2*>(h2 + (size_t)(base + lane) * NCLS + wid * 10);
        hp[0] = make_float2(acc[0], acc[1]);
        hp[1] = make_float2(acc[2], acc[3]);
        hp[2] = make_float2(acc[4], acc[5]);
        hp[3] = make_float2(acc[6], acc[7]);
        hp[4] = make_float2(acc[8], acc[9]);
    }
}

// ---------- aggregations (wave per node, lane = feature, 8x unrolled) ----------
__global__ __launch_bounds__(256) void k_agg1(const float* __restrict__ h1,
                                              const int* __restrict__ rowptr,
                                              const int2* __restrict__ edges,
                                              const float* __restrict__ dinv,
                                              const float* __restrict__ b1,
                                              float* __restrict__ y, int n) {
    int lane = threadIdx.x & 63;
    int wid = threadIdx.x >> 6;
    for (int node = blockIdx.x * 4 + wid; node < n; node += gridDim.x * 4) {
        int i = __builtin_amdgcn_readfirstlane(node);
        float di = dinv[i];
        float a0 = di * di * h1[(size_t)i * HID + lane];
        float a1 = 0.f, a2 = 0.f, a3 = 0.f, a4 = 0.f, a5 = 0.f, a6 = 0.f, a7 = 0.f;
        int s = rowptr[i], e = rowptr[i + 1];
        int p = s;
        for (; p + 8 <= e; p += 8) {
            int2 e0 = edges[p], e1 = edges[p + 1], e2 = edges[p + 2], e3 = edges[p + 3];
            int2 e4 = edges[p + 4], e5 = edges[p + 5], e6 = edges[p + 6], e7 = edges[p + 7];
            a0 = fmaf(__int_as_float(e0.y), h1[(size_t)e0.x * HID + lane], a0);
            a1 = fmaf(__int_as_float(e1.y), h1[(size_t)e1.x * HID + lane], a1);
            a2 = fmaf(__int_as_float(e2.y), h1[(size_t)e2.x * HID + lane], a2);
            a3 = fmaf(__int_as_float(e3.y), h1[(size_t)e3.x * HID + lane], a3);
            a4 = fmaf(__int_as_float(e4.y), h1[(size_t)e4.x * HID + lane], a4);
            a5 = fmaf(__int_as_float(e5.y), h1[(size_t)e5.x * HID + lane], a5);
            a6 = fmaf(__int_as_float(e6.y), h1[(size_t)e6.x * HID + lane], a6);
            a7 = fmaf(__int_as_float(e7.y), h1[(size_t)e7.x * HID + lane], a7);
        }
        for (; p + 4 <= e; p += 4) {
            int2 e0 = edges[p], e1 = edges[p + 1], e2 = edges[p + 2], e3 = edges[p + 3];
            a0 = fmaf(__int_as_float(e0.y), h1[(size_t)e0.x * HID + lane], a0);
            a1 = fmaf(__int_as_float(e1.y), h1[(size_t)e1.x * HID + lane], a1);
            a2 = fmaf(__int_as_float(e2.y), h1[(size_t)e2.x * HID + lane], a2);
            a3 = fmaf(__int_as_float(e3.y), h1[(size_t)e3.x * HID + lane], a3);
        }
        for (; p < e; p++) {
            int2 e0 = edges[p];
            a0 = fmaf(__int_as_float(e0.y), h1[(size_t)e0.x * HID + lane], a0);
        }
        float acc = ((a0 + a1) + (a2 + a3)) + ((a4 + a5) + (a6 + a7)) + b1[lane];
        y[(size_t)i * HID + lane] = fmaxf(acc, 0.f);
    }
}

__global__ __launch_bounds__(256) void k_agg2(const float* __restrict__ h2,
                                              const int* __restrict__ rowptr,
                                              const int2* __restrict__ edges,
                                              const float* __restrict__ dinv,
                                              const float* __restrict__ b2,
                                              float* __restrict__ out, int n) {
    int lane = threadIdx.x & 63;
    int wid = threadIdx.x >> 6;
    for (int node = blockIdx.x * 4 + wid; node < n; node += gridDim.x * 4) {
        int i = __builtin_amdgcn_readfirstlane(node);
        float di = dinv[i];
        int c = lane < NCLS ? lane : 0;
        float a0 = di * di * h2[(size_t)i * NCLS + c];
        float a1 = 0.f, a2 = 0.f, a3 = 0.f, a4 = 0.f, a5 = 0.f, a6 = 0.f, a7 = 0.f;
        int s = rowptr[i], e = rowptr[i + 1];
        int p = s;
        for (; p + 8 <= e; p += 8) {
            int2 e0 = edges[p], e1 = edges[p + 1], e2 = edges[p + 2], e3 = edges[p + 3];
            int2 e4 = edges[p + 4], e5 = edges[p + 5], e6 = edges[p + 6], e7 = edges[p + 7];
            a0 = fmaf(__int_as_float(e0.y), h2[(size_t)e0.x * NCLS + c], a0);
            a1 = fmaf(__int_as_float(e1.y), h2[(size_t)e1.x * NCLS + c], a1);
            a2 = fmaf(__int_as_float(e2.y), h2[(size_t)e2.x * NCLS + c], a2);
            a3 = fmaf(__int_as_float(e3.y), h2[(size_t)e3.x * NCLS + c], a3);
            a4 = fmaf(__int_as_float(e4.y), h2[(size_t)e4.x * NCLS + c], a4);
            a5 = fmaf(__int_as_float(e5.y), h2[(size_t)e5.x * NCLS + c], a5);
            a6 = fmaf(__int_as_float(e6.y), h2[(size_t)e6.x * NCLS + c], a6);
            a7 = fmaf(__int_as_float(e7.y), h2[(size_t)e7.x * NCLS + c], a7);
        }
        for (; p + 4 <= e; p += 4) {
            int2 e0 = edges[p], e1 = edges[p + 1], e2 = edges[p + 2], e3 = edges[p + 3];
            a0 = fmaf(__int_as_float(e0.y), h2[(size_t)e0.x * NCLS + c], a0);
            a1 = fmaf(__int_as_float(e1.y), h2[(size_t)e1.x * NCLS + c], a1);
            a2 = fmaf(__int_as_float(e2.y), h2[(size_t)e2.x * NCLS + c], a2);
            a3 = fmaf(__int_as_float(e3.y), h2[(size_t)e3.x * NCLS + c], a3);
        }
        for (; p < e; p++) {
            int2 e0 = edges[p];
            a0 = fmaf(__int_as_float(e0.y), h2[(size_t)e0.x * NCLS + c], a0);
        }
        float acc = ((a0 + a1) + (a2 + a3)) + ((a4 + a5) + (a6 + a7)) + b2[c];
        float z = lane < NCLS ? acc : -INFINITY;
        float m = z;
#pragma unroll
        for (int off = 32; off > 0; off >>= 1) m = fmaxf(m, __shfl_xor(m, off));
        float ex = lane < NCLS ? expf(z - m) : 0.f;
        float ssum = ex;
#pragma unroll
        for (int off = 32; off > 0; off >>= 1) ssum += __shfl_xor(ssum, off);
        if (lane < NCLS) out[(size_t)i * NCLS + lane] = z - m - logf(ssum);
    }
}

// ---------------- launch ----------------

extern "C" void kernel_launch(void* const* d_in, const int* in_sizes, int n_in,
                              void* d_out, int out_size, void* d_ws, size_t ws_size,
                              hipStream_t stream) {
    const float* x = (const float*)d_in[0];
    const int* edge_index = (const int*)d_in[1];
    const float* ew = (const float*)d_in[2];
    const float* W1 = (const float*)d_in[3];
    const float* b1 = (const float*)d_in[4];
    const float* W2 = (const float*)d_in[5];
    const float* b2 = (const float*)d_in[6];
    float* out = (float*)d_out;

    const int N = in_sizes[0] / NFEAT;      // 100000
    const int E = in_sizes[2];              // 1600000
    const int* src = edge_index;
    const int* dst = edge_index + E;

    const int NBUK = (N + 127) >> BSH;      // 782
    const int EPB = (E + PB - 1) / PB;      // 3125

    char* ws = (char*)d_ws;
    size_t off = 0;
    auto alloc = [&](size_t bytes) { void* p = ws + off; off = (off + bytes + 255) & ~(size_t)255; return p; };
    int*   ghist    = (int*)alloc((size_t)NBUK_MAX * PB * 4);   // 2 MB
    int*   buktot   = (int*)alloc(4096);
    int*   bukstart = (int*)alloc(4096 + 4);
    int*   rowptr   = (int*)alloc((size_t)(N + 1) * 4);
    float* dinv     = (float*)alloc((size_t)N * 4);
    int2*  edges    = (int2*)alloc((size_t)E * 8);              // 12.8 MB
    float* y        = (float*)alloc((size_t)N * HID * 4);       // 25.6 MB
    // sedge dead after k_bucket_csr; h1 (25.6 MB) aliases it
    unsigned long long* sedge = (unsigned long long*)alloc((size_t)N * HID * 4);
    float* h1 = (float*)sedge;
    float* h2 = h1;                                             // h1 dead after agg1

    k_hist<<<PB, 256, 0, stream>>>(dst, ghist, E, NBUK, EPB);
    k_colscan<<<NBUK, 256, 0, stream>>>(ghist, buktot, NBUK);
    k_bukscan<<<1, 256, 0, stream>>>(buktot, bukstart, rowptr, NBUK, N, E);
    k_bucketize<<<PB, 256, 0, stream>>>(src, dst, ew, ghist, bukstart, sedge, E, NBUK, EPB);
    k_bucket_csr<<<NBUK, 256, 0, stream>>>(sedge, bukstart, rowptr, dinv, edges, N);
    k_norm<<<NBUK, 256, 0, stream>>>(bukstart, dinv, edges, N);
    k_gemm1<<<(N + 63) / 64, 256, 0, stream>>>(x, W1, h1, N);
    k_agg1<<<(N + 3) / 4, 256, 0, stream>>>(h1, rowptr, edges, dinv, b1, y, N);
    k_gemm2<<<(N + 63) / 64, 256, 0, stream>>>(y, W2, h2, N);
    k_agg2<<<(N + 3) / 4, 256, 0, stream>>>(h2, rowptr, edges, dinv, b2, out, N);
}

// Round 7
// 306.447 us; speedup vs baseline: 2.1629x; 1.0956x over previous
//
#include <hip/hip_runtime.h>
#include <hip/hip_bf16.h>
#include <math.h>

// GCN 2-layer: x[N,128] @ W1 -> agg -> relu -> @ W2 -> agg -> log_softmax
// N=100000, E=1600000, F=128, H=64, C=40
// CSR via LDS bucket counting-sort (zero global atomics).
// h1/h2 stored bf16 to halve random-gather traffic in agg passes.

#define NFEAT 128
#define HID 64
#define NCLS 40
#define PB 512          // partition blocks for hist/bucketize
#define BSH 7           // 128 nodes per bucket
#define NBUK_MAX 1024

static __device__ __forceinline__ unsigned short f2bf(float f) {
    unsigned u = __float_as_uint(f);
    unsigned r = (u + 0x7fffu + ((u >> 16) & 1u)) >> 16;
    return (unsigned short)r;
}
static __device__ __forceinline__ float bf2f(unsigned short b) {
    return __uint_as_float(((unsigned)b) << 16);
}

// ---------- Pass A: per-block bucket histogram ----------
__global__ __launch_bounds__(256) void k_hist(const int* __restrict__ dst,
                                              int* __restrict__ ghist,
                                              int e, int nbuk, int epb) {
    __shared__ int hist[NBUK_MAX];
    for (int j = threadIdx.x; j < nbuk; j += 256) hist[j] = 0;
    __syncthreads();
    int b = blockIdx.x;
    int lo = b * epb, hi = min(lo + epb, e);
    for (int i = lo + threadIdx.x; i < hi; i += 256)
        atomicAdd(&hist[dst[i] >> BSH], 1);
    __syncthreads();
    for (int j = threadIdx.x; j < nbuk; j += 256) ghist[j * PB + b] = hist[j];
}

// ---------- Pass B1: exclusive scan of each bucket's column (in place) ----------
__global__ __launch_bounds__(256) void k_colscan(int* __restrict__ ghist,
                                                 int* __restrict__ buktot, int nbuk) {
    __shared__ int s[256];
    int k = blockIdx.x, t = threadIdx.x;
    int* col = ghist + k * PB;
    int v0 = col[2 * t], v1 = col[2 * t + 1];
    int sum = v0 + v1;
    s[t] = sum; __syncthreads();
    for (int off = 1; off < 256; off <<= 1) {
        int x = (t >= off) ? s[t - off] : 0;
        __syncthreads();
        s[t] += x;
        __syncthreads();
    }
    int excl = s[t] - sum;
    col[2 * t] = excl;
    col[2 * t + 1] = excl + v0;
    if (t == 255) buktot[k] = s[255];
}

// ---------- Pass B2: scan bucket totals -> bukstart ----------
__global__ __launch_bounds__(256) void k_bukscan(const int* __restrict__ buktot,
                                                 int* __restrict__ bukstart,
                                                 int* __restrict__ rowptr,
                                                 int nbuk, int n, int e) {
    __shared__ int s[256];
    int t = threadIdx.x;
    int v[4]; int sum = 0;
#pragma unroll
    for (int j = 0; j < 4; j++) { int idx = t * 4 + j; v[j] = (idx < nbuk) ? buktot[idx] : 0; sum += v[j]; }
    s[t] = sum; __syncthreads();
    for (int off = 1; off < 256; off <<= 1) {
        int x = (t >= off) ? s[t - off] : 0;
        __syncthreads();
        s[t] += x;
        __syncthreads();
    }
    int excl = s[t] - sum;
#pragma unroll
    for (int j = 0; j < 4; j++) { int idx = t * 4 + j; if (idx < nbuk) bukstart[idx] = excl; excl += v[j]; }
    if (t == 255) bukstart[nbuk] = s[255];
    if (t == 0) rowptr[n] = e;
}

// ---------- Pass C: scatter edges into bucket-sorted order (LDS atomics only) ----------
__global__ __launch_bounds__(256) void k_bucketize(const int* __restrict__ src,
                                                   const int* __restrict__ dst,
                                                   const float* __restrict__ w,
                                                   const int* __restrict__ ghist,
                                                   const int* __restrict__ bukstart,
                                                   unsigned long long* __restrict__ sedge,
                                                   int e, int nbuk, int epb) {
    __shared__ int loff[NBUK_MAX];
    int b = blockIdx.x;
    for (int j = threadIdx.x; j < nbuk; j += 256) loff[j] = bukstart[j] + ghist[j * PB + b];
    __syncthreads();
    int lo = b * epb, hi = min(lo + epb, e);
    for (int i = lo + threadIdx.x; i < hi; i += 256) {
        int d = dst[i], s = src[i];
        int k = d >> BSH;
        int pos = atomicAdd(&loff[k], 1);
        unsigned long long rec = ((unsigned long long)__float_as_uint(w[i]) << 32)
                               | ((unsigned)(d & 127) << 17) | (unsigned)s;
        sedge[pos] = rec;
    }
}

// ---------- Pass D: per-bucket CSR + degree (LDS float adds) ----------
__global__ __launch_bounds__(256) void k_bucket_csr(const unsigned long long* __restrict__ sedge,
                                                    const int* __restrict__ bukstart,
                                                    int* __restrict__ rowptr,
                                                    float* __restrict__ dinv,
                                                    int2* __restrict__ edges, int n) {
    __shared__ int cnt[128]; __shared__ float wsum[128];
    __shared__ int fill[128]; __shared__ int rloc[128];
    int k = blockIdx.x, t = threadIdx.x;
    int base = k << BSH;
    int nloc = n - base; if (nloc > 128) nloc = 128;
    if (t < 128) { cnt[t] = 0; fill[t] = 0; wsum[t] = 1.0f; }   // 1.0 = self-loop weight
    __syncthreads();
    int lo = bukstart[k], hi = bukstart[k + 1];
    for (int p = lo + t; p < hi; p += 256) {
        unsigned long long r = sedge[p];
        int dloc = (int)((r >> 17) & 127);
        atomicAdd(&cnt[dloc], 1);
        atomicAdd(&wsum[dloc], __uint_as_float((unsigned)(r >> 32)));
    }
    __syncthreads();
    if (t < 128) rloc[t] = cnt[t];
    __syncthreads();
    for (int off = 1; off < 128; off <<= 1) {
        int x = 0;
        if (t < 128 && t >= off) x = rloc[t - off];
        __syncthreads();
        if (t < 128) rloc[t] += x;
        __syncthreads();
    }
    if (t < 128) {
        int excl = rloc[t] - cnt[t];
        rloc[t] = excl;
        if (t < nloc) {
            rowptr[base + t] = lo + excl;
            dinv[base + t] = rsqrtf(wsum[t]);   // deg >= 1 (self loop)
        }
    }
    __syncthreads();
    for (int p = lo + t; p < hi; p += 256) {
        unsigned long long r = sedge[p];
        int dloc = (int)((r >> 17) & 127);
        int srcn = (int)(r & 0x1ffff);
        int pos = lo + rloc[dloc] + atomicAdd(&fill[dloc], 1);
        edges[pos] = make_int2((dloc << 17) | srcn, (int)(unsigned)(r >> 32)); // keep dloc+raw w
    }
}

// ---------- Pass E: normalize edge values in place ----------
__global__ __launch_bounds__(256) void k_norm(const int* __restrict__ bukstart,
                                              const float* __restrict__ dinv,
                                              int2* __restrict__ edges, int n) {
    int k = blockIdx.x;
    int base = k << BSH;
    int lo = bukstart[k], hi = bukstart[k + 1];
    for (int p = lo + threadIdx.x; p < hi; p += 256) {
        int2 rec = edges[p];
        int dloc = rec.x >> 17, srcn = rec.x & 0x1ffff;
        float v = __int_as_float(rec.y) * dinv[srcn] * dinv[base + dloc];
        edges[p] = make_int2(srcn, __float_as_int(v));
    }
}

// ---------- GEMM1: 64-row tiles, x transposed in LDS, bf16 output ----------
__global__ __launch_bounds__(256) void k_gemm1(const float* __restrict__ x,
                                               const float* __restrict__ W1,
                                               unsigned short* __restrict__ h1, int n) {
    __shared__ float xs[64 * 65];
    int t = threadIdx.x;
    int lane = t & 63;
    int wid = __builtin_amdgcn_readfirstlane(t >> 6);
    int base = blockIdx.x * 64;
    int nrows = n - base; if (nrows > 64) nrows = 64;
    const float4* xg = reinterpret_cast<const float4*>(x + (size_t)base * NFEAT);
    float acc[16];
#pragma unroll
    for (int c = 0; c < 16; c++) acc[c] = 0.f;
#pragma unroll
    for (int h = 0; h < 2; h++) {
        for (int j = t; j < nrows * 16; j += 256) {
            int row = j >> 4, k4 = j & 15;
            float4 v = xg[row * 32 + h * 16 + k4];
            xs[(4 * k4 + 0) * 65 + row] = v.x;
            xs[(4 * k4 + 1) * 65 + row] = v.y;
            xs[(4 * k4 + 2) * 65 + row] = v.z;
            xs[(4 * k4 + 3) * 65 + row] = v.w;
        }
        __syncthreads();
        const float* wb = W1 + (size_t)(h * 64) * HID + wid * 16;
#pragma unroll 4
        for (int k = 0; k < 64; k++) {
            float xv = xs[k * 65 + lane];
            const float* wk = wb + k * HID;
#pragma unroll
            for (int c = 0; c < 16; c++) acc[c] = fmaf(wk[c], xv, acc[c]);
        }
        __syncthreads();
    }
    if (lane < nrows) {
        unsigned pk[8];
#pragma unroll
        for (int j = 0; j < 8; j++)
            pk[j] = (unsigned)f2bf(acc[2 * j]) | ((unsigned)f2bf(acc[2 * j + 1]) << 16);
        uint4* hp = reinterpret_cast<uint4*>(h1 + (size_t)(base + lane) * HID + wid * 16);
        hp[0] = make_uint4(pk[0], pk[1], pk[2], pk[3]);
        hp[1] = make_uint4(pk[4], pk[5], pk[6], pk[7]);
    }
}

// ---------- GEMM2: y fp32 in, bf16 out ----------
__global__ __launch_bounds__(256) void k_gemm2(const float* __restrict__ y,
                                               const float* __restrict__ W2,
                                               unsigned short* __restrict__ h2, int n) {
    __shared__ float ys[HID * 65];
    int t = threadIdx.x;
    int lane = t & 63;
    int wid = __builtin_amdgcn_readfirstlane(t >> 6);
    int base = blockIdx.x * 64;
    int nrows = n - base; if (nrows > 64) nrows = 64;
    const float4* yg = reinterpret_cast<const float4*>(y + (size_t)base * HID);
    for (int j = t; j < nrows * 16; j += 256) {
        int row = j >> 4, k4 = j & 15;
        float4 v = yg[j];
        ys[(4 * k4 + 0) * 65 + row] = v.x;
        ys[(4 * k4 + 1) * 65 + row] = v.y;
        ys[(4 * k4 + 2) * 65 + row] = v.z;
        ys[(4 * k4 + 3) * 65 + row] = v.w;
    }
    __syncthreads();
    const float* wb = W2 + wid * 10;
    float acc[10];
#pragma unroll
    for (int c = 0; c < 10; c++) acc[c] = 0.f;
#pragma unroll 4
    for (int k = 0; k < HID; k++) {
        float yv = ys[k * 65 + lane];
        const float* wk = wb + k * NCLS;
#pragma unroll
        for (int c = 0; c < 10; c++) acc[c] = fmaf(wk[c], yv, acc[c]);
    }
    if (lane < nrows) {
        unsigned* hp = reinterpret_cast<unsigned*>(h2 + (size_t)(base + lane) * NCLS + wid * 10);
#pragma unroll
        for (int j = 0; j < 5; j++)
            hp[j] = (unsigned)f2bf(acc[2 * j]) | ((unsigned)f2bf(acc[2 * j + 1]) << 16);
    }
}

// ---------- aggregations (wave per node, lane = feature, 8x unrolled, bf16 gathers) ----------
__global__ __launch_bounds__(256) void k_agg1(const unsigned short* __restrict__ h1,
                                              const int* __restrict__ rowptr,
                                              const int2* __restrict__ edges,
                                              const float* __restrict__ dinv,
                                              const float* __restrict__ b1,
                                              float* __restrict__ y, int n) {
    int lane = threadIdx.x & 63;
    int wid = threadIdx.x >> 6;
    for (int node = blockIdx.x * 4 + wid; node < n; node += gridDim.x * 4) {
        int i = __builtin_amdgcn_readfirstlane(node);
        float di = dinv[i];
        float a0 = di * di * bf2f(h1[(size_t)i * HID + lane]);
        float a1 = 0.f, a2 = 0.f, a3 = 0.f, a4 = 0.f, a5 = 0.f, a6 = 0.f, a7 = 0.f;
        int s = rowptr[i], e = rowptr[i + 1];
        int p = s;
        for (; p + 8 <= e; p += 8) {
            int2 e0 = edges[p], e1 = edges[p + 1], e2 = edges[p + 2], e3 = edges[p + 3];
            int2 e4 = edges[p + 4], e5 = edges[p + 5], e6 = edges[p + 6], e7 = edges[p + 7];
            a0 = fmaf(__int_as_float(e0.y), bf2f(h1[(size_t)e0.x * HID + lane]), a0);
            a1 = fmaf(__int_as_float(e1.y), bf2f(h1[(size_t)e1.x * HID + lane]), a1);
            a2 = fmaf(__int_as_float(e2.y), bf2f(h1[(size_t)e2.x * HID + lane]), a2);
            a3 = fmaf(__int_as_float(e3.y), bf2f(h1[(size_t)e3.x * HID + lane]), a3);
            a4 = fmaf(__int_as_float(e4.y), bf2f(h1[(size_t)e4.x * HID + lane]), a4);
            a5 = fmaf(__int_as_float(e5.y), bf2f(h1[(size_t)e5.x * HID + lane]), a5);
            a6 = fmaf(__int_as_float(e6.y), bf2f(h1[(size_t)e6.x * HID + lane]), a6);
            a7 = fmaf(__int_as_float(e7.y), bf2f(h1[(size_t)e7.x * HID + lane]), a7);
        }
        for (; p + 4 <= e; p += 4) {
            int2 e0 = edges[p], e1 = edges[p + 1], e2 = edges[p + 2], e3 = edges[p + 3];
            a0 = fmaf(__int_as_float(e0.y), bf2f(h1[(size_t)e0.x * HID + lane]), a0);
            a1 = fmaf(__int_as_float(e1.y), bf2f(h1[(size_t)e1.x * HID + lane]), a1);
            a2 = fmaf(__int_as_float(e2.y), bf2f(h1[(size_t)e2.x * HID + lane]), a2);
            a3 = fmaf(__int_as_float(e3.y), bf2f(h1[(size_t)e3.x * HID + lane]), a3);
        }
        for (; p < e; p++) {
            int2 e0 = edges[p];
            a0 = fmaf(__int_as_float(e0.y), bf2f(h1[(size_t)e0.x * HID + lane]), a0);
        }
        float acc = ((a0 + a1) + (a2 + a3)) + ((a4 + a5) + (a6 + a7)) + b1[lane];
        y[(size_t)i * HID + lane] = fmaxf(acc, 0.f);
    }
}

__global__ __launch_bounds__(256) void k_agg2(const unsigned short* __restrict__ h2,
                                              const int* __restrict__ rowptr,
                                              const int2* __restrict__ edges,
                                              const float* __restrict__ dinv,
                                              const float* __restrict__ b2,
                                              float* __restrict__ out, int n) {
    int lane = threadIdx.x & 63;
    int wid = threadIdx.x >> 6;
    for (int node = blockIdx.x * 4 + wid; node < n; node += gridDim.x * 4) {
        int i = __builtin_amdgcn_readfirstlane(node);
        float di = dinv[i];
        int c = lane < NCLS ? lane : 0;
        float a0 = di * di * bf2f(h2[(size_t)i * NCLS + c]);
        float a1 = 0.f, a2 = 0.f, a3 = 0.f, a4 = 0.f, a5 = 0.f, a6 = 0.f, a7 = 0.f;
        int s = rowptr[i], e = rowptr[i + 1];
        int p = s;
        for (; p + 8 <= e; p += 8) {
            int2 e0 = edges[p], e1 = edges[p + 1], e2 = edges[p + 2], e3 = edges[p + 3];
            int2 e4 = edges[p + 4], e5 = edges[p + 5], e6 = edges[p + 6], e7 = edges[p + 7];
            a0 = fmaf(__int_as_float(e0.y), bf2f(h2[(size_t)e0.x * NCLS + c]), a0);
            a1 = fmaf(__int_as_float(e1.y), bf2f(h2[(size_t)e1.x * NCLS + c]), a1);
            a2 = fmaf(__int_as_float(e2.y), bf2f(h2[(size_t)e2.x * NCLS + c]), a2);
            a3 = fmaf(__int_as_float(e3.y), bf2f(h2[(size_t)e3.x * NCLS + c]), a3);
            a4 = fmaf(__int_as_float(e4.y), bf2f(h2[(size_t)e4.x * NCLS + c]), a4);
            a5 = fmaf(__int_as_float(e5.y), bf2f(h2[(size_t)e5.x * NCLS + c]), a5);
            a6 = fmaf(__int_as_float(e6.y), bf2f(h2[(size_t)e6.x * NCLS + c]), a6);
            a7 = fmaf(__int_as_float(e7.y), bf2f(h2[(size_t)e7.x * NCLS + c]), a7);
        }
        for (; p + 4 <= e; p += 4) {
            int2 e0 = edges[p], e1 = edges[p + 1], e2 = edges[p + 2], e3 = edges[p + 3];
            a0 = fmaf(__int_as_float(e0.y), bf2f(h2[(size_t)e0.x * NCLS + c]), a0);
            a1 = fmaf(__int_as_float(e1.y), bf2f(h2[(size_t)e1.x * NCLS + c]), a1);
            a2 = fmaf(__int_as_float(e2.y), bf2f(h2[(size_t)e2.x * NCLS + c]), a2);
            a3 = fmaf(__int_as_float(e3.y), bf2f(h2[(size_t)e3.x * NCLS + c]), a3);
        }
        for (; p < e; p++) {
            int2 e0 = edges[p];
            a0 = fmaf(__int_as_float(e0.y), bf2f(h2[(size_t)e0.x * NCLS + c]), a0);
        }
        float acc = ((a0 + a1) + (a2 + a3)) + ((a4 + a5) + (a6 + a7)) + b2[c];
        float z = lane < NCLS ? acc : -INFINITY;
        float m = z;
#pragma unroll
        for (int off = 32; off > 0; off >>= 1) m = fmaxf(m, __shfl_xor(m, off));
        float ex = lane < NCLS ? expf(z - m) : 0.f;
        float ssum = ex;
#pragma unroll
        for (int off = 32; off > 0; off >>= 1) ssum += __shfl_xor(ssum, off);
        if (lane < NCLS) out[(size_t)i * NCLS + lane] = z - m - logf(ssum);
    }
}

// ---------------- launch ----------------

extern "C" void kernel_launch(void* const* d_in, const int* in_sizes, int n_in,
                              void* d_out, int out_size, void* d_ws, size_t ws_size,
                              hipStream_t stream) {
    const float* x = (const float*)d_in[0];
    const int* edge_index = (const int*)d_in[1];
    const float* ew = (const float*)d_in[2];
    const float* W1 = (const float*)d_in[3];
    const float* b1 = (const float*)d_in[4];
    const float* W2 = (const float*)d_in[5];
    const float* b2 = (const float*)d_in[6];
    float* out = (float*)d_out;

    const int N = in_sizes[0] / NFEAT;      // 100000
    const int E = in_sizes[2];              // 1600000
    const int* src = edge_index;
    const int* dst = edge_index + E;

    const int NBUK = (N + 127) >> BSH;      // 782
    const int EPB = (E + PB - 1) / PB;      // 3125

    char* ws = (char*)d_ws;
    size_t off = 0;
    auto alloc = [&](size_t bytes) { void* p = ws + off; off = (off + bytes + 255) & ~(size_t)255; return p; };
    int*   ghist    = (int*)alloc((size_t)NBUK_MAX * PB * 4);   // 2 MB
    int*   buktot   = (int*)alloc(4096);
    int*   bukstart = (int*)alloc(4096 + 4);
    int*   rowptr   = (int*)alloc((size_t)(N + 1) * 4);
    float* dinv     = (float*)alloc((size_t)N * 4);
    int2*  edges    = (int2*)alloc((size_t)E * 8);              // 12.8 MB
    float* y        = (float*)alloc((size_t)N * HID * 4);       // 25.6 MB
    // sedge dead after k_bucket_csr; h1 (bf16, 12.8 MB) aliases it
    unsigned long long* sedge = (unsigned long long*)alloc((size_t)E * 8);
    unsigned short* h1 = (unsigned short*)sedge;
    unsigned short* h2 = h1;                                    // h1 dead after agg1

    k_hist<<<PB, 256, 0, stream>>>(dst, ghist, E, NBUK, EPB);
    k_colscan<<<NBUK, 256, 0, stream>>>(ghist, buktot, NBUK);
    k_bukscan<<<1, 256, 0, stream>>>(buktot, bukstart, rowptr, NBUK, N, E);
    k_bucketize<<<PB, 256, 0, stream>>>(src, dst, ew, ghist, bukstart, sedge, E, NBUK, EPB);
    k_bucket_csr<<<NBUK, 256, 0, stream>>>(sedge, bukstart, rowptr, dinv, edges, N);
    k_norm<<<NBUK, 256, 0, stream>>>(bukstart, dinv, edges, N);
    k_gemm1<<<(N + 63) / 64, 256, 0, stream>>>(x, W1, h1, N);
    k_agg1<<<(N + 3) / 4, 256, 0, stream>>>(h1, rowptr, edges, dinv, b1, y, N);
    k_gemm2<<<(N + 63) / 64, 256, 0, stream>>>(y, W2, h2, N);
    k_agg2<<<(N + 3) / 4, 256, 0, stream>>>(h2, rowptr, edges, dinv, b2, out, N);
}